// Round 9
// baseline (290.506 us; speedup 1.0000x reference)
//
#include <hip/hip_runtime.h>
#include <hip/hip_bf16.h>

#define B_ 256
#define L_ 100
#define F_ 8
#define P_ 4
#define E_ 64
#define H_ 4
#define D_ 64
#define C_ 32
#define V_ 10000
#define TOWER_IN_ 1312
#define LN_EPS 0.001f
#define LCH_ 4    // l's per attention block
#define NCH_ 25   // number of l-chunks
#define ZK_ 40    // padded k-stride for sZt (80B: 16B-aligned, conflict-free)

typedef __attribute__((ext_vector_type(8))) short bf8v;           // 8 bf16 (4 VGPRs)
typedef __attribute__((ext_vector_type(8))) unsigned short us8;   // 8 u16
typedef __attribute__((ext_vector_type(4))) float f4v;            // 4 f32 acc

__device__ __forceinline__ unsigned short f2bf(float x) {
    __hip_bfloat16 h = __float2bfloat16(x);
    return __builtin_bit_cast(unsigned short, h);
}

// raw barrier: LDS-drain + s_barrier, NO vmcnt drain (prefetch loads stay in flight)
#define BARRIER() do { \
    asm volatile("s_waitcnt lgkmcnt(0)" ::: "memory"); \
    __builtin_amdgcn_s_barrier(); \
    asm volatile("" ::: "memory"); \
} while (0)

// ---------------------------------------------------------------------------
// Kernel PRE: precomp (register-tiled f32) + ubs_acc zero.
// ---------------------------------------------------------------------------
__global__ __launch_bounds__(256) void pre_kernel(
    const float* __restrict__ q_w, const float* __restrict__ k_w,
    const float* __restrict__ v_w, const float* __restrict__ lin_w,
    unsigned short* __restrict__ wsMT, unsigned short* __restrict__ wsWT,
    float* __restrict__ ubs_acc)
{
    __shared__ float sA[64][68];
    __shared__ float sB[64][68];
    const int t = threadIdx.x;
    const int bx = blockIdx.x;

    if (bx >= 400) {
        const int bi = bx - 400;                   // 128 blocks x 1024 floats
        float4 z = {0.f, 0.f, 0.f, 0.f};
        *(float4*)(ubs_acc + (size_t)bi * 1024 + t * 4) = z;
        return;
    }

    const int l = bx >> 2;
    const int h = bx & 3;
    const size_t obase = (size_t)(l * 4 + h) * 4096;
    const int te = t & 15, to = t >> 4;

    for (int i = 0; i < 16; ++i) {
        int idx = t + i * 256;
        int e = idx >> 6, d = idx & 63;
        sA[e][d] = q_w[(l * 64 + e) * 256 + h * 64 + d];
        sB[e][d] = k_w[(l * 64 + e) * 256 + h * 64 + d];
    }
    __syncthreads();
    {
        float acc[4][4];
        #pragma unroll
        for (int i = 0; i < 4; ++i)
            #pragma unroll
            for (int j = 0; j < 4; ++j) acc[i][j] = 0.f;
        for (int d0 = 0; d0 < 64; d0 += 4) {
            float4 a4[4], b4[4];
            #pragma unroll
            for (int i = 0; i < 4; ++i) a4[i] = *(const float4*)&sA[te + 16 * i][d0];
            #pragma unroll
            for (int j = 0; j < 4; ++j) b4[j] = *(const float4*)&sB[to + 16 * j][d0];
            #pragma unroll
            for (int i = 0; i < 4; ++i)
                #pragma unroll
                for (int j = 0; j < 4; ++j) {
                    acc[i][j] += a4[i].x * b4[j].x;
                    acc[i][j] += a4[i].y * b4[j].y;
                    acc[i][j] += a4[i].z * b4[j].z;
                    acc[i][j] += a4[i].w * b4[j].w;
                }
        }
        #pragma unroll
        for (int j = 0; j < 4; ++j)
            #pragma unroll
            for (int i = 0; i < 4; ++i)
                wsMT[obase + (to + 16 * j) * 64 + (te + 16 * i)] = f2bf(acc[i][j]);
    }
    __syncthreads();

    for (int i = 0; i < 16; ++i) {
        int idx = t + i * 256;
        int e = idx >> 6, d = idx & 63;
        sA[e][d] = v_w[(l * 64 + e) * 256 + h * 64 + d];
        int oo = idx & 63, dd = idx >> 6;
        sB[oo][dd] = lin_w[l * 16384 + (h * 64 + dd) * 64 + oo];
    }
    __syncthreads();
    {
        float acc[4][4];
        #pragma unroll
        for (int i = 0; i < 4; ++i)
            #pragma unroll
            for (int j = 0; j < 4; ++j) acc[i][j] = 0.f;
        for (int d0 = 0; d0 < 64; d0 += 4) {
            float4 a4[4], b4[4];
            #pragma unroll
            for (int i = 0; i < 4; ++i) a4[i] = *(const float4*)&sA[te + 16 * i][d0];
            #pragma unroll
            for (int j = 0; j < 4; ++j) b4[j] = *(const float4*)&sB[to + 16 * j][d0];
            #pragma unroll
            for (int i = 0; i < 4; ++i)
                #pragma unroll
                for (int j = 0; j < 4; ++j) {
                    acc[i][j] += a4[i].x * b4[j].x;
                    acc[i][j] += a4[i].y * b4[j].y;
                    acc[i][j] += a4[i].z * b4[j].z;
                    acc[i][j] += a4[i].w * b4[j].w;
                }
        }
        #pragma unroll
        for (int j = 0; j < 4; ++j)
            #pragma unroll
            for (int i = 0; i < 4; ++i)
                wsWT[obase + (to + 16 * j) * 64 + (te + 16 * i)] = f2bf(acc[i][j]);
    }
}

// ---------------------------------------------------------------------------
// Kernel A: fused attention for chunks [c0, c0+nch) + optional prep blocks
// (launch A only).  attn body identical to R5/R8 (passing).
// ---------------------------------------------------------------------------
__global__ __launch_bounds__(256, 3) void attn_kernel(
    const int* __restrict__ ubs_feature, const float* __restrict__ item_tables,
    const unsigned short* __restrict__ wsMT, const unsigned short* __restrict__ wsWT,
    const float* __restrict__ lin_b, const float* __restrict__ ln_g,
    const float* __restrict__ ln_b, float* __restrict__ ubs_acc,
    const float* __restrict__ w1, const float* __restrict__ w2,
    const float* __restrict__ w3,
    unsigned short* __restrict__ Wt1, unsigned short* __restrict__ Wt2,
    unsigned short* __restrict__ Wt3, int c0, int nch)
{
    __shared__ __align__(16) unsigned short sUE[64][72];       // rows=b_loc*8+f
    __shared__ __align__(16) unsigned short sT[64][136];       // cols=hl*64+e'
    __shared__ __align__(16) unsigned short sZt[4][64][ZK_];   // [pair][e][k] (k<32 used)
    __shared__ __align__(16) unsigned short sAblk[4][16][32];  // [pair][r][k]
    __shared__ float sLng[64], sLnb[64], sLinb[LCH_][64];

    const int t = threadIdx.x;

    if ((int)blockIdx.x >= nch * 32) {
        // ---------------- prep (weight transpose), launch A only ------------
        float (*tile)[33] = (float (*)[33])sT;   // 32x33 f32 fits in sT region
        int bi = blockIdx.x - nch * 32;
        const float* src; unsigned short* dst; int K, N, tk, tn;
        if (bi < 1312)      { src = w1; dst = Wt1; K = 1312; N = 1024; tk = bi / 32;  tn = bi % 32; }
        else if (bi < 1824) { int i = bi - 1312; src = w2; dst = Wt2; K = 1024; N = 512; tk = i / 16; tn = i % 16; }
        else                { int i = bi - 1824; src = w3; dst = Wt3; K = 512;  N = 256; tk = i / 8;  tn = i % 8; }
        const int k0 = tk * 32, n0 = tn * 32;
        const int rr = t >> 5, cc = t & 31;
        #pragma unroll
        for (int i = 0; i < 4; ++i) {
            int r = rr * 4 + i;
            tile[r][cc] = src[(size_t)(k0 + r) * N + n0 + cc];
        }
        __syncthreads();
        #pragma unroll
        for (int i = 0; i < 4; ++i) {
            int r = rr * 4 + i;
            dst[(size_t)(n0 + r) * K + k0 + cc] = f2bf(tile[cc][r]);
        }
        return;
    }

    const int c = c0 + (blockIdx.x >> 5);      // l-chunk
    const int b0 = (blockIdx.x & 31) * 8;
    const int wv = t >> 6, lane = t & 63, quad = lane >> 4, cl = lane & 15;
    const int role = wv >> 1, hlw = wv & 1;

    const int grow = wv * 16 + (lane >> 2);   // row in [0,64) = b_loc*8 + f
    const int gseg = lane & 3;                // 16-float segment
    const int gb = b0 + (grow >> 3), gf = grow & 7;

    if (t < 64) { sLng[t] = ln_g[t]; sLnb[t] = ln_b[t]; }
    if (t >= 64 && t < 128) {
        #pragma unroll
        for (int li = 0; li < LCH_; ++li)
            sLinb[li][t - 64] = lin_b[(c * LCH_ + li) * 64 + (t - 64)];
    }

    int vidx[LCH_];
    #pragma unroll
    for (int li = 0; li < LCH_; ++li)
        vidx[li] = ubs_feature[(gb * L_ + c * LCH_ + li) * F_ + gf];

    float4 pf[4];
    bf8v bfrag[4][2];

    auto load_bfrag = [&](int lh) {   // lh = l*4 + half*2 + hlw
        const unsigned short* Bsrc = (role == 0 ? wsMT : wsWT) + ((size_t)lh * 4096);
        #pragma unroll
        for (int nt = 0; nt < 4; ++nt)
            #pragma unroll
            for (int k2 = 0; k2 < 2; ++k2)
                bfrag[nt][k2] = *(const bf8v*)(Bsrc + (nt * 16 + cl) * 64 + k2 * 32 + quad * 8);
    };
    auto load_pf = [&](int li) {
        const float* srcp = item_tables + ((size_t)gf * V_ + vidx[li]) * 64 + gseg * 16;
        #pragma unroll
        for (int j = 0; j < 4; ++j) pf[j] = ((const float4*)srcp)[j];
    };
    auto store_ue = [&]() {
        us8 u0, u1;
        u0[0] = f2bf(pf[0].x); u0[1] = f2bf(pf[0].y); u0[2] = f2bf(pf[0].z); u0[3] = f2bf(pf[0].w);
        u0[4] = f2bf(pf[1].x); u0[5] = f2bf(pf[1].y); u0[6] = f2bf(pf[1].z); u0[7] = f2bf(pf[1].w);
        u1[0] = f2bf(pf[2].x); u1[1] = f2bf(pf[2].y); u1[2] = f2bf(pf[2].z); u1[3] = f2bf(pf[2].w);
        u1[4] = f2bf(pf[3].x); u1[5] = f2bf(pf[3].y); u1[6] = f2bf(pf[3].z); u1[7] = f2bf(pf[3].w);
        *(us8*)&sUE[grow][gseg * 16]     = u0;
        *(us8*)&sUE[grow][gseg * 16 + 8] = u1;
    };

    load_pf(0);
    load_bfrag((c * LCH_) * 4 + hlw);
    store_ue();
    BARRIER();

    float lnacc[16];
    #pragma unroll
    for (int i = 0; i < 16; ++i) lnacc[i] = 0.f;

    for (int li = 0; li < LCH_; ++li) {
        const int l = c * LCH_ + li;

        if (li + 1 < LCH_) load_pf(li + 1);

        f4v accO[4];
        #pragma unroll
        for (int nt = 0; nt < 4; ++nt) accO[nt] = {0.f, 0.f, 0.f, 0.f};

        #pragma unroll
        for (int half = 0; half < 2; ++half) {
            #pragma unroll
            for (int m = 0; m < 4; ++m) {
                bf8v a0 = *(const bf8v*)&sUE[m * 16 + cl][quad * 8];
                bf8v a1 = *(const bf8v*)&sUE[m * 16 + cl][32 + quad * 8];
                #pragma unroll
                for (int nt = 0; nt < 4; ++nt) {
                    f4v acc = {0.f, 0.f, 0.f, 0.f};
                    acc = __builtin_amdgcn_mfma_f32_16x16x32_bf16(a0, bfrag[nt][0], acc, 0, 0, 0);
                    acc = __builtin_amdgcn_mfma_f32_16x16x32_bf16(a1, bfrag[nt][1], acc, 0, 0, 0);
                    if (role == 0) {
                        #pragma unroll
                        for (int j = 0; j < 4; ++j)
                            sT[m * 16 + quad * 4 + j][hlw * 64 + nt * 16 + cl] = f2bf(acc[j]);
                    } else {
                        ushort4 zp;
                        zp.x = f2bf(acc[0]); zp.y = f2bf(acc[1]);
                        zp.z = f2bf(acc[2]); zp.w = f2bf(acc[3]);
                        const int k0 = (quad >> 1) * 16 + hlw * 8 + (quad & 1) * 4;
                        *(ushort4*)&sZt[m][nt * 16 + cl][k0] = zp;
                    }
                }
            }
            if (half == 0)            load_bfrag(l * 4 + 2 + hlw);
            else if (li + 1 < LCH_)   load_bfrag((l + 1) * 4 + hlw);
            BARRIER();

            {
                const int p = wv;
                const bool valid = (cl >> 3) == (quad >> 1);
                #pragma unroll
                for (int hl = 0; hl < 2; ++hl) {
                    bf8v a0s = *(const bf8v*)&sT[p * 16 + cl][hl * 64 + quad * 8];
                    bf8v a1s = *(const bf8v*)&sT[p * 16 + cl][hl * 64 + 32 + quad * 8];
                    bf8v u0 = *(const bf8v*)&sUE[p * 16 + cl][quad * 8];
                    bf8v u1 = *(const bf8v*)&sUE[p * 16 + cl][32 + quad * 8];
                    f4v acc = {0.f, 0.f, 0.f, 0.f};
                    acc = __builtin_amdgcn_mfma_f32_16x16x32_bf16(a0s, u0, acc, 0, 0, 0);
                    acc = __builtin_amdgcn_mfma_f32_16x16x32_bf16(a1s, u1, acc, 0, 0, 0);
                    const int kk = hl * 8 + (cl & 7) + (cl >> 3) * 16;
                    #pragma unroll
                    for (int j = 0; j < 4; ++j) {
                        float v = acc[j] * 0.125f;
                        float mx = v;
                        mx = fmaxf(mx, __shfl_xor(mx, 1));
                        mx = fmaxf(mx, __shfl_xor(mx, 2));
                        mx = fmaxf(mx, __shfl_xor(mx, 4));
                        float ex = __expf(v - mx);
                        float sm = ex;
                        sm += __shfl_xor(sm, 1);
                        sm += __shfl_xor(sm, 2);
                        sm += __shfl_xor(sm, 4);
                        float aw = valid ? ex * __builtin_amdgcn_rcpf(sm) : 0.f;
                        sAblk[p][quad * 4 + j][kk] = f2bf(aw);
                    }
                }
            }

            {
                const int p = wv;
                bf8v a0p = *(const bf8v*)&sAblk[p][cl][quad * 8];
                #pragma unroll
                for (int nt = 0; nt < 4; ++nt) {
                    bf8v bz = *(const bf8v*)&sZt[p][nt * 16 + cl][quad * 8];
                    accO[nt] = __builtin_amdgcn_mfma_f32_16x16x32_bf16(a0p, bz, accO[nt], 0, 0, 0);
                }
            }
            BARRIER();
        }

        {
            float x[16];
            #pragma unroll
            for (int nt = 0; nt < 4; ++nt)
                #pragma unroll
                for (int j = 0; j < 4; ++j)
                    x[nt * 4 + j] = accO[nt][j] + sLinb[li][nt * 16 + cl];
            #pragma unroll
            for (int j = 0; j < 4; ++j) {
                float s = x[j] + x[4 + j] + x[8 + j] + x[12 + j];
                #pragma unroll
                for (int m = 1; m < 16; m <<= 1) s += __shfl_xor(s, m);
                float mean = s * (1.f / 64.f);
                float q = 0.f;
                #pragma unroll
                for (int nt = 0; nt < 4; ++nt) { float d = x[nt * 4 + j] - mean; q += d * d; }
                #pragma unroll
                for (int m = 1; m < 16; m <<= 1) q += __shfl_xor(q, m);
                float rst = rsqrtf(q * (1.f / 64.f) + LN_EPS);
                #pragma unroll
                for (int nt = 0; nt < 4; ++nt) {
                    int col = nt * 16 + cl;
                    lnacc[nt * 4 + j] += (x[nt * 4 + j] - mean) * rst * sLng[col] + sLnb[col];
                }
            }
        }

        if (li + 1 < LCH_) {
            store_ue();
            BARRIER();
        }
    }

    #pragma unroll
    for (int j = 0; j < 4; ++j) {
        const int row = wv * 16 + quad * 4 + j;
        const int b = b0 + (row >> 3), f = row & 7;
        #pragma unroll
        for (int nt = 0; nt < 4; ++nt)
            atomicAdd(&ubs_acc[(size_t)b * 512 + f * 64 + nt * 16 + cl], lnacc[nt * 4 + j]);
    }
}

// ---------------------------------------------------------------------------
// gemm core: C[m0..+16][n0..+64] += LDS-A . Bw^T + bias.  4 waves, 16 col/wave.
// ---------------------------------------------------------------------------
__device__ __forceinline__ void gemm_from_lds(
    const unsigned short* sA, int lda,
    const unsigned short* __restrict__ Bw, const float* __restrict__ bias,
    float* __restrict__ Cd, int K, int N, int n0w, int m0,
    int quad, int cl)
{
    f4v acc0 = {0.f, 0.f, 0.f, 0.f};
    f4v acc1 = {0.f, 0.f, 0.f, 0.f};
    const unsigned short* arow = sA + cl * lda + quad * 8;
    const unsigned short* brow = Bw + (size_t)(n0w + cl) * K + quad * 8;
    int k0 = 0;
    for (; k0 + 64 <= K; k0 += 64) {
        bf8v a0 = *(const bf8v*)(arow + k0);
        bf8v b0 = *(const bf8v*)(brow + k0);
        bf8v a1 = *(const bf8v*)(arow + k0 + 32);
        bf8v b1 = *(const bf8v*)(brow + k0 + 32);
        acc0 = __builtin_amdgcn_mfma_f32_16x16x32_bf16(a0, b0, acc0, 0, 0, 0);
        acc1 = __builtin_amdgcn_mfma_f32_16x16x32_bf16(a1, b1, acc1, 0, 0, 0);
    }
    if (k0 < K) {
        bf8v a = *(const bf8v*)(arow + k0);
        bf8v b = *(const bf8v*)(brow + k0);
        acc0 = __builtin_amdgcn_mfma_f32_16x16x32_bf16(a, b, acc0, 0, 0, 0);
    }
    float bv = bias[n0w + cl];
    #pragma unroll
    for (int j = 0; j < 4; ++j)
        Cd[(size_t)(m0 + quad * 4 + j) * N + n0w + cl] = acc0[j] + acc1[j] + bv;
}

// ---------------------------------------------------------------------------
// LN-from-C into LDS bf16 (per-block, 16 rows, N cols).  row = t>>4, sub = t&15.
// ---------------------------------------------------------------------------
__device__ __forceinline__ void ln_rows_to_lds(
    const float* __restrict__ Cd, int N, int m0,
    const float* __restrict__ g, const float* __restrict__ bb,
    unsigned short* sH, int lda, int t, float invN)
{
    const int r = t >> 4, sub = t & 15;
    const float* crow = Cd + (size_t)(m0 + r) * N;
    float s = 0.f, s2 = 0.f;
    for (int j = sub * 4; j < N; j += 64) {
        float4 x = *(const float4*)(crow + j);
        s  += x.x + x.y + x.z + x.w;
        s2 += x.x * x.x + x.y * x.y + x.z * x.z + x.w * x.w;
    }
    #pragma unroll
    for (int m = 1; m < 16; m <<= 1) { s += __shfl_xor(s, m); s2 += __shfl_xor(s2, m); }
    const float mean = s * invN;
    const float var  = s2 * invN - mean * mean;
    const float rst  = rsqrtf(fmaxf(var, 0.f) + LN_EPS);
    for (int j = sub * 4; j < N; j += 64) {
        float4 x = *(const float4*)(crow + j);
        ushort4 o;
        o.x = f2bf(fmaxf((x.x - mean) * rst * g[j]     + bb[j],     0.f));
        o.y = f2bf(fmaxf((x.y - mean) * rst * g[j + 1] + bb[j + 1], 0.f));
        o.z = f2bf(fmaxf((x.z - mean) * rst * g[j + 2] + bb[j + 2], 0.f));
        o.w = f2bf(fmaxf((x.w - mean) * rst * g[j + 3] + bb[j + 3], 0.f));
        *(ushort4*)&sH[r * lda + j] = o;
    }
}

// ---------------------------------------------------------------------------
// Kernel G1: X-build (LDS) + gemm1 -> C1 f32.  grid (16 n x 16 m) = 256 blocks.
// ---------------------------------------------------------------------------
#define XLD 1320
__global__ __launch_bounds__(256) void gemm1x_kernel(
    const float* __restrict__ ubs_acc,
    const int* __restrict__ target_ad, const int* __restrict__ profile_feature,
    const float* __restrict__ context,
    const float* __restrict__ item_tables, const float* __restrict__ profile_tables,
    const unsigned short* __restrict__ Wt1, const float* __restrict__ b1,
    float* __restrict__ C1)
{
    __shared__ __align__(16) unsigned short sX[16][XLD];
    const int t = threadIdx.x;
    const int wv = t >> 6, lane = t & 63, quad = lane >> 4, cl = lane & 15;
    const int m0 = (blockIdx.x >> 4) * 16;
    const int n0w = (blockIdx.x & 15) * 64 + wv * 16;

    {
        const int r = t >> 4, sub = t & 15;
        const int gb = m0 + r;
        #pragma unroll
        for (int k = 0; k < 21; ++k) {
            int cc = sub * 4 + k * 64;
            if (cc >= TOWER_IN_) break;
            float4 x;
            if (cc < 512) {
                x = *(const float4*)(ubs_acc + (size_t)gb * 512 + cc);
                x.x = fmaxf(x.x * 0.01f, 0.f); x.y = fmaxf(x.y * 0.01f, 0.f);
                x.z = fmaxf(x.z * 0.01f, 0.f); x.w = fmaxf(x.w * 0.01f, 0.f);
            } else if (cc < 1024) {
                int f = (cc - 512) >> 6, e = (cc - 512) & 63;
                x = *(const float4*)(item_tables + ((size_t)f * V_ + target_ad[gb * 8 + f]) * 64 + e);
            } else if (cc < 1280) {
                int pp = (cc - 1024) >> 6, e = (cc - 1024) & 63;
                x = *(const float4*)(profile_tables + ((size_t)pp * V_ + profile_feature[gb * 4 + pp]) * 64 + e);
            } else {
                x = *(const float4*)(context + (size_t)gb * 32 + (cc - 1280));
            }
            ushort4 o;
            o.x = f2bf(x.x); o.y = f2bf(x.y); o.z = f2bf(x.z); o.w = f2bf(x.w);
            *(ushort4*)&sX[r][cc] = o;
        }
    }
    __syncthreads();
    gemm_from_lds(&sX[0][0], XLD, Wt1, b1, C1, 1312, 1024, n0w, m0, quad, cl);
}

// ---------------------------------------------------------------------------
// Kernel G2: LN1(C1)+ReLU (LDS) + gemm2 -> C2 f32.  grid (8 n x 16 m) = 128.
// ---------------------------------------------------------------------------
#define H1LD 1032
__global__ __launch_bounds__(256) void gemm2f_kernel(
    const float* __restrict__ C1, const float* __restrict__ g1,
    const float* __restrict__ bb1,
    const unsigned short* __restrict__ Wt2, const float* __restrict__ b2,
    float* __restrict__ C2)
{
    __shared__ __align__(16) unsigned short sH[16][H1LD];
    const int t = threadIdx.x;
    const int wv = t >> 6, lane = t & 63, quad = lane >> 4, cl = lane & 15;
    const int m0 = (blockIdx.x >> 3) * 16;
    const int n0w = (blockIdx.x & 7) * 64 + wv * 16;

    ln_rows_to_lds(C1, 1024, m0, g1, bb1, &sH[0][0], H1LD, t, 1.f / 1024.f);
    __syncthreads();
    gemm_from_lds(&sH[0][0], H1LD, Wt2, b2, C2, 1024, 512, n0w, m0, quad, cl);
}

// ---------------------------------------------------------------------------
// Kernel G3: LN2(C2)+ReLU (LDS) + gemm3 (full 256-col rows) + LN3 + ReLU +
// dot(w4) + sigmoid -> out.  grid = 16 blocks (16 rows each), 256 threads.
// ---------------------------------------------------------------------------
#define H2LD 520
__global__ __launch_bounds__(256) void gemm3f_kernel(
    const float* __restrict__ C2, const float* __restrict__ g2,
    const float* __restrict__ bb2,
    const unsigned short* __restrict__ Wt3, const float* __restrict__ b3,
    const float* __restrict__ g3, const float* __restrict__ bb3,
    const float* __restrict__ w4, const float* __restrict__ b4,
    float* __restrict__ out)
{
    __shared__ __align__(16) unsigned short sH[16][H2LD];
    __shared__ float sS[4][16], sQ[4][16], sP[4][16];
    const int t = threadIdx.x;
    const int wv = t >> 6, lane = t & 63, quad = lane >> 4, cl = lane & 15;
    const int m0 = blockIdx.x * 16;

    ln_rows_to_lds(C2, 512, m0, g2, bb2, &sH[0][0], H2LD, t, 1.f / 512.f);
    __syncthreads();

    f4v acc[4];
    #pragma unroll
    for (int nt = 0; nt < 4; ++nt) acc[nt] = {0.f, 0.f, 0.f, 0.f};
    for (int k0 = 0; k0 < 512; k0 += 32) {
        bf8v a = *(const bf8v*)&sH[cl][k0 + quad * 8];
        #pragma unroll
        for (int nt = 0; nt < 4; ++nt) {
            const int col0 = wv * 64 + nt * 16;
            bf8v b = *(const bf8v*)(Wt3 + (size_t)(col0 + cl) * 512 + k0 + quad * 8);
            acc[nt] = __builtin_amdgcn_mfma_f32_16x16x32_bf16(a, b, acc[nt], 0, 0, 0);
        }
    }
    #pragma unroll
    for (int nt = 0; nt < 4; ++nt) {
        float bv = b3[wv * 64 + nt * 16 + cl];
        #pragma unroll
        for (int j = 0; j < 4; ++j) acc[nt][j] += bv;
    }

    #pragma unroll
    for (int j = 0; j < 4; ++j) {
        float s = acc[0][j] + acc[1][j] + acc[2][j] + acc[3][j];
        float q = acc[0][j]*acc[0][j] + acc[1][j]*acc[1][j] + acc[2][j]*acc[2][j] + acc[3][j]*acc[3][j];
        #pragma unroll
        for (int m = 1; m < 16; m <<= 1) { s += __shfl_xor(s, m); q += __shfl_xor(q, m); }
        if (cl == 0) { sS[wv][quad * 4 + j] = s; sQ[wv][quad * 4 + j] = q; }
    }
    __syncthreads();
    float meanr[4], rstdr[4];
    #pragma unroll
    for (int j = 0; j < 4; ++j) {
        const int row = quad * 4 + j;
        float s = sS[0][row] + sS[1][row] + sS[2][row] + sS[3][row];
        float q = sQ[0][row] + sQ[1][row] + sQ[2][row] + sQ[3][row];
        float mean = s * (1.f / 256.f);
        float var  = q * (1.f / 256.f) - mean * mean;
        meanr[j] = mean;
        rstdr[j] = rsqrtf(fmaxf(var, 0.f) + LN_EPS);
    }

    #pragma unroll
    for (int j = 0; j < 4; ++j) {
        float p = 0.f;
        #pragma unroll
        for (int nt = 0; nt < 4; ++nt) {
            const int col = wv * 64 + nt * 16 + cl;
            float h = fmaxf((acc[nt][j] - meanr[j]) * rstdr[j] * g3[col] + bb3[col], 0.f);
            p += h * w4[col];
        }
        #pragma unroll
        for (int m = 1; m < 16; m <<= 1) p += __shfl_xor(p, m);
        if (cl == 0) sP[wv][quad * 4 + j] = p;
    }
    __syncthreads();
    if (t < 16) {
        float p = sP[0][t] + sP[1][t] + sP[2][t] + sP[3][t];
        out[m0 + t] = 1.f / (1.f + expf(-(p + b4[0])));
    }
}

// ---------------------------------------------------------------------------
extern "C" void kernel_launch(void* const* d_in, const int* in_sizes, int n_in,
                              void* d_out, int out_size, void* d_ws, size_t ws_size,
                              hipStream_t stream)
{
    (void)in_sizes; (void)n_in; (void)out_size; (void)ws_size;
    const int*   target_ad       = (const int*)d_in[0];
    const int*   ubs_feature     = (const int*)d_in[1];
    const int*   profile_feature = (const int*)d_in[2];
    const float* context         = (const float*)d_in[3];
    const float* item_tables     = (const float*)d_in[4];
    const float* profile_tables  = (const float*)d_in[5];
    const float* q_w   = (const float*)d_in[6];
    const float* k_w   = (const float*)d_in[7];
    const float* v_w   = (const float*)d_in[8];
    const float* lin_w = (const float*)d_in[9];
    const float* lin_b = (const float*)d_in[10];
    const float* ln_g  = (const float*)d_in[11];
    const float* ln_b  = (const float*)d_in[12];
    const float* t_w1  = (const float*)d_in[13];
    const float* t_b1  = (const float*)d_in[14];
    const float* t_g1  = (const float*)d_in[15];
    const float* t_bb1 = (const float*)d_in[16];
    const float* t_w2  = (const float*)d_in[17];
    const float* t_b2  = (const float*)d_in[18];
    const float* t_g2  = (const float*)d_in[19];
    const float* t_bb2 = (const float*)d_in[20];
    const float* t_w3  = (const float*)d_in[21];
    const float* t_b3  = (const float*)d_in[22];
    const float* t_g3  = (const float*)d_in[23];
    const float* t_bb3 = (const float*)d_in[24];
    const float* t_w4  = (const float*)d_in[25];
    const float* t_b4  = (const float*)d_in[26];

    char* ws = (char*)d_ws;
    unsigned short* wsMT = (unsigned short*)(ws);              //  3,276,800
    unsigned short* wsWT = (unsigned short*)(ws +  3276800);   //  3,276,800
    float* ubs_acc       = (float*)         (ws +  6553600);   //    524,288
    unsigned short* Wt1  = (unsigned short*)(ws +  7077888);   //  2,686,976
    unsigned short* Wt2  = (unsigned short*)(ws +  9764864);   //  1,048,576
    unsigned short* Wt3  = (unsigned short*)(ws + 10813440);   //    262,144
    float*          C1   = (float*)         (ws + 11075584);   //  1,048,576
    float*          C2   = (float*)         (ws + 12124160);   //    524,288 (end 12,648,448)

    pre_kernel<<<528, 256, 0, stream>>>(q_w, k_w, v_w, lin_w, wsMT, wsWT, ubs_acc);
    // attn split 3 ways (9+8+8 chunks); prep rides on launch A.
    attn_kernel<<<9 * 32 + 1952, 256, 0, stream>>>(ubs_feature, item_tables, wsMT, wsWT,
                                                   lin_b, ln_g, ln_b, ubs_acc,
                                                   t_w1, t_w2, t_w3, Wt1, Wt2, Wt3, 0, 9);
    attn_kernel<<<8 * 32, 256, 0, stream>>>(ubs_feature, item_tables, wsMT, wsWT,
                                            lin_b, ln_g, ln_b, ubs_acc,
                                            t_w1, t_w2, t_w3, Wt1, Wt2, Wt3, 9, 8);
    attn_kernel<<<8 * 32, 256, 0, stream>>>(ubs_feature, item_tables, wsMT, wsWT,
                                            lin_b, ln_g, ln_b, ubs_acc,
                                            t_w1, t_w2, t_w3, Wt1, Wt2, Wt3, 17, 8);
    gemm1x_kernel<<<256, 256, 0, stream>>>(ubs_acc, target_ad, profile_feature, context,
                                           item_tables, profile_tables, Wt1, t_b1, C1);
    gemm2f_kernel<<<128, 256, 0, stream>>>(C1, t_g1, t_bb1, Wt2, t_b2, C2);
    gemm3f_kernel<<<16, 256, 0, stream>>>(C2, t_g2, t_bb2, Wt3, t_b3,
                                          t_g3, t_bb3, t_w4, t_b4, (float*)d_out);
}

// Round 10
// 261.736 us; speedup vs baseline: 1.1099x; 1.1099x over previous
//
#include <hip/hip_runtime.h>
#include <hip/hip_bf16.h>

#define B_ 256
#define L_ 100
#define F_ 8
#define P_ 4
#define E_ 64
#define H_ 4
#define D_ 64
#define C_ 32
#define V_ 10000
#define TOWER_IN_ 1312
#define LN_EPS 0.001f
#define LCH_ 4    // l's per attention block
#define NCH_ 25   // number of l-chunks
#define ZK_ 40    // padded k-stride for sZt (80B: 16B-aligned, conflict-free)

typedef __attribute__((ext_vector_type(8))) short bf8v;           // 8 bf16 (4 VGPRs)
typedef __attribute__((ext_vector_type(8))) unsigned short us8;   // 8 u16
typedef __attribute__((ext_vector_type(4))) float f4v;            // 4 f32 acc

__device__ __forceinline__ unsigned short f2bf(float x) {
    __hip_bfloat16 h = __float2bfloat16(x);
    return __builtin_bit_cast(unsigned short, h);
}

// raw barrier: LDS-drain + s_barrier, NO vmcnt drain (prefetch loads stay in flight)
#define BARRIER() do { \
    asm volatile("s_waitcnt lgkmcnt(0)" ::: "memory"); \
    __builtin_amdgcn_s_barrier(); \
    asm volatile("" ::: "memory"); \
} while (0)

// ---------------------------------------------------------------------------
// Kernel PRE: precomp (register-tiled f32) + ubs_acc zero.
// ---------------------------------------------------------------------------
__global__ __launch_bounds__(256) void pre_kernel(
    const float* __restrict__ q_w, const float* __restrict__ k_w,
    const float* __restrict__ v_w, const float* __restrict__ lin_w,
    unsigned short* __restrict__ wsMT, unsigned short* __restrict__ wsWT,
    float* __restrict__ ubs_acc)
{
    __shared__ float sA[64][68];
    __shared__ float sB[64][68];
    const int t = threadIdx.x;
    const int bx = blockIdx.x;

    if (bx >= 400) {
        const int bi = bx - 400;                   // 128 blocks x 1024 floats
        float4 z = {0.f, 0.f, 0.f, 0.f};
        *(float4*)(ubs_acc + (size_t)bi * 1024 + t * 4) = z;
        return;
    }

    const int l = bx >> 2;
    const int h = bx & 3;
    const size_t obase = (size_t)(l * 4 + h) * 4096;
    const int te = t & 15, to = t >> 4;

    for (int i = 0; i < 16; ++i) {
        int idx = t + i * 256;
        int e = idx >> 6, d = idx & 63;
        sA[e][d] = q_w[(l * 64 + e) * 256 + h * 64 + d];
        sB[e][d] = k_w[(l * 64 + e) * 256 + h * 64 + d];
    }
    __syncthreads();
    {
        float acc[4][4];
        #pragma unroll
        for (int i = 0; i < 4; ++i)
            #pragma unroll
            for (int j = 0; j < 4; ++j) acc[i][j] = 0.f;
        for (int d0 = 0; d0 < 64; d0 += 4) {
            float4 a4[4], b4[4];
            #pragma unroll
            for (int i = 0; i < 4; ++i) a4[i] = *(const float4*)&sA[te + 16 * i][d0];
            #pragma unroll
            for (int j = 0; j < 4; ++j) b4[j] = *(const float4*)&sB[to + 16 * j][d0];
            #pragma unroll
            for (int i = 0; i < 4; ++i)
                #pragma unroll
                for (int j = 0; j < 4; ++j) {
                    acc[i][j] += a4[i].x * b4[j].x;
                    acc[i][j] += a4[i].y * b4[j].y;
                    acc[i][j] += a4[i].z * b4[j].z;
                    acc[i][j] += a4[i].w * b4[j].w;
                }
        }
        #pragma unroll
        for (int j = 0; j < 4; ++j)
            #pragma unroll
            for (int i = 0; i < 4; ++i)
                wsMT[obase + (to + 16 * j) * 64 + (te + 16 * i)] = f2bf(acc[i][j]);
    }
    __syncthreads();

    for (int i = 0; i < 16; ++i) {
        int idx = t + i * 256;
        int e = idx >> 6, d = idx & 63;
        sA[e][d] = v_w[(l * 64 + e) * 256 + h * 64 + d];
        int oo = idx & 63, dd = idx >> 6;
        sB[oo][dd] = lin_w[l * 16384 + (h * 64 + dd) * 64 + oo];
    }
    __syncthreads();
    {
        float acc[4][4];
        #pragma unroll
        for (int i = 0; i < 4; ++i)
            #pragma unroll
            for (int j = 0; j < 4; ++j) acc[i][j] = 0.f;
        for (int d0 = 0; d0 < 64; d0 += 4) {
            float4 a4[4], b4[4];
            #pragma unroll
            for (int i = 0; i < 4; ++i) a4[i] = *(const float4*)&sA[te + 16 * i][d0];
            #pragma unroll
            for (int j = 0; j < 4; ++j) b4[j] = *(const float4*)&sB[to + 16 * j][d0];
            #pragma unroll
            for (int i = 0; i < 4; ++i)
                #pragma unroll
                for (int j = 0; j < 4; ++j) {
                    acc[i][j] += a4[i].x * b4[j].x;
                    acc[i][j] += a4[i].y * b4[j].y;
                    acc[i][j] += a4[i].z * b4[j].z;
                    acc[i][j] += a4[i].w * b4[j].w;
                }
        }
        #pragma unroll
        for (int j = 0; j < 4; ++j)
            #pragma unroll
            for (int i = 0; i < 4; ++i)
                wsWT[obase + (to + 16 * j) * 64 + (te + 16 * i)] = f2bf(acc[i][j]);
    }
}

// ---------------------------------------------------------------------------
// Kernel A: fused attention (blocks < 800) + tower weight prep (blocks >= 800).
// Single launch (800 attn blocks: 3/CU co-residency matters — R9 lesson).
// Changes vs R8: 4 barriers/l (store_ue moved before half-1's post-PV barrier;
// safe: scores reads only the wave's own 16 sUE rows) + u0/u1 hoisted.
// ---------------------------------------------------------------------------
__global__ __launch_bounds__(256, 3) void attn_kernel(
    const int* __restrict__ ubs_feature, const float* __restrict__ item_tables,
    const unsigned short* __restrict__ wsMT, const unsigned short* __restrict__ wsWT,
    const float* __restrict__ lin_b, const float* __restrict__ ln_g,
    const float* __restrict__ ln_b, float* __restrict__ ubs_acc,
    const float* __restrict__ w1, const float* __restrict__ w2,
    const float* __restrict__ w3,
    unsigned short* __restrict__ Wt1, unsigned short* __restrict__ Wt2,
    unsigned short* __restrict__ Wt3)
{
    __shared__ __align__(16) unsigned short sUE[64][72];       // rows=b_loc*8+f
    __shared__ __align__(16) unsigned short sT[64][136];       // cols=hl*64+e'
    __shared__ __align__(16) unsigned short sZt[4][64][ZK_];   // [pair][e][k] (k<32 used)
    __shared__ __align__(16) unsigned short sAblk[4][16][32];  // [pair][r][k]
    __shared__ float sLng[64], sLnb[64], sLinb[LCH_][64];

    const int t = threadIdx.x;

    if (blockIdx.x >= 800) {
        // ---------------- prep (weight transpose) ----------------
        float (*tile)[33] = (float (*)[33])sT;   // 32x33 f32 fits in sT region
        int bi = blockIdx.x - 800;
        const float* src; unsigned short* dst; int K, N, tk, tn;
        if (bi < 1312)      { src = w1; dst = Wt1; K = 1312; N = 1024; tk = bi / 32;  tn = bi % 32; }
        else if (bi < 1824) { int i = bi - 1312; src = w2; dst = Wt2; K = 1024; N = 512; tk = i / 16; tn = i % 16; }
        else                { int i = bi - 1824; src = w3; dst = Wt3; K = 512;  N = 256; tk = i / 8;  tn = i % 8; }
        const int k0 = tk * 32, n0 = tn * 32;
        const int rr = t >> 5, cc = t & 31;
        #pragma unroll
        for (int i = 0; i < 4; ++i) {
            int r = rr * 4 + i;
            tile[r][cc] = src[(size_t)(k0 + r) * N + n0 + cc];
        }
        __syncthreads();
        #pragma unroll
        for (int i = 0; i < 4; ++i) {
            int r = rr * 4 + i;
            dst[(size_t)(n0 + r) * K + k0 + cc] = f2bf(tile[cc][r]);
        }
        return;
    }

    const int c = blockIdx.x >> 5;            // l-chunk 0..24
    const int b0 = (blockIdx.x & 31) * 8;
    const int wv = t >> 6, lane = t & 63, quad = lane >> 4, cl = lane & 15;
    const int role = wv >> 1, hlw = wv & 1;

    const int grow = wv * 16 + (lane >> 2);   // row in [0,64) = b_loc*8 + f
    const int gseg = lane & 3;                // 16-float segment
    const int gb = b0 + (grow >> 3), gf = grow & 7;

    if (t < 64) { sLng[t] = ln_g[t]; sLnb[t] = ln_b[t]; }
    if (t >= 64 && t < 128) {
        #pragma unroll
        for (int li = 0; li < LCH_; ++li)
            sLinb[li][t - 64] = lin_b[(c * LCH_ + li) * 64 + (t - 64)];
    }

    int vidx[LCH_];
    #pragma unroll
    for (int li = 0; li < LCH_; ++li)
        vidx[li] = ubs_feature[(gb * L_ + c * LCH_ + li) * F_ + gf];

    float4 pf[4];
    bf8v bfrag[4][2];

    auto load_bfrag = [&](int lh) {   // lh = l*4 + half*2 + hlw
        const unsigned short* Bsrc = (role == 0 ? wsMT : wsWT) + ((size_t)lh * 4096);
        #pragma unroll
        for (int nt = 0; nt < 4; ++nt)
            #pragma unroll
            for (int k2 = 0; k2 < 2; ++k2)
                bfrag[nt][k2] = *(const bf8v*)(Bsrc + (nt * 16 + cl) * 64 + k2 * 32 + quad * 8);
    };
    auto load_pf = [&](int li) {
        const float* srcp = item_tables + ((size_t)gf * V_ + vidx[li]) * 64 + gseg * 16;
        #pragma unroll
        for (int j = 0; j < 4; ++j) pf[j] = ((const float4*)srcp)[j];
    };
    auto store_ue = [&]() {
        us8 u0, u1;
        u0[0] = f2bf(pf[0].x); u0[1] = f2bf(pf[0].y); u0[2] = f2bf(pf[0].z); u0[3] = f2bf(pf[0].w);
        u0[4] = f2bf(pf[1].x); u0[5] = f2bf(pf[1].y); u0[6] = f2bf(pf[1].z); u0[7] = f2bf(pf[1].w);
        u1[0] = f2bf(pf[2].x); u1[1] = f2bf(pf[2].y); u1[2] = f2bf(pf[2].z); u1[3] = f2bf(pf[2].w);
        u1[4] = f2bf(pf[3].x); u1[5] = f2bf(pf[3].y); u1[6] = f2bf(pf[3].z); u1[7] = f2bf(pf[3].w);
        *(us8*)&sUE[grow][gseg * 16]     = u0;
        *(us8*)&sUE[grow][gseg * 16 + 8] = u1;
    };

    load_pf(0);
    load_bfrag((c * LCH_) * 4 + hlw);
    store_ue();
    BARRIER();

    float lnacc[16];
    #pragma unroll
    for (int i = 0; i < 16; ++i) lnacc[i] = 0.f;

    for (int li = 0; li < LCH_; ++li) {
        const int l = c * LCH_ + li;

        if (li + 1 < LCH_) load_pf(li + 1);

        f4v accO[4];
        #pragma unroll
        for (int nt = 0; nt < 4; ++nt) accO[nt] = {0.f, 0.f, 0.f, 0.f};

        #pragma unroll
        for (int half = 0; half < 2; ++half) {
            // ---- phase A: waves 0,1 -> T; waves 2,3 -> Zt ----
            #pragma unroll
            for (int m = 0; m < 4; ++m) {
                bf8v a0 = *(const bf8v*)&sUE[m * 16 + cl][quad * 8];
                bf8v a1 = *(const bf8v*)&sUE[m * 16 + cl][32 + quad * 8];
                #pragma unroll
                for (int nt = 0; nt < 4; ++nt) {
                    f4v acc = {0.f, 0.f, 0.f, 0.f};
                    acc = __builtin_amdgcn_mfma_f32_16x16x32_bf16(a0, bfrag[nt][0], acc, 0, 0, 0);
                    acc = __builtin_amdgcn_mfma_f32_16x16x32_bf16(a1, bfrag[nt][1], acc, 0, 0, 0);
                    if (role == 0) {
                        #pragma unroll
                        for (int j = 0; j < 4; ++j)
                            sT[m * 16 + quad * 4 + j][hlw * 64 + nt * 16 + cl] = f2bf(acc[j]);
                    } else {
                        ushort4 zp;
                        zp.x = f2bf(acc[0]); zp.y = f2bf(acc[1]);
                        zp.z = f2bf(acc[2]); zp.w = f2bf(acc[3]);
                        const int k0 = (quad >> 1) * 16 + hlw * 8 + (quad & 1) * 4;
                        *(ushort4*)&sZt[m][nt * 16 + cl][k0] = zp;
                    }
                }
            }
            if (half == 0)            load_bfrag(l * 4 + 2 + hlw);
            else if (li + 1 < LCH_)   load_bfrag((l + 1) * 4 + hlw);
            BARRIER();

            // ---- scores + softmax + Ablk (wave = pair) ----
            {
                const int p = wv;
                const bool valid = (cl >> 3) == (quad >> 1);
                // u0/u1 are hl-independent: hoisted (was 4 b128 reads, now 2)
                bf8v u0 = *(const bf8v*)&sUE[p * 16 + cl][quad * 8];
                bf8v u1 = *(const bf8v*)&sUE[p * 16 + cl][32 + quad * 8];
                #pragma unroll
                for (int hl = 0; hl < 2; ++hl) {
                    bf8v a0s = *(const bf8v*)&sT[p * 16 + cl][hl * 64 + quad * 8];
                    bf8v a1s = *(const bf8v*)&sT[p * 16 + cl][hl * 64 + 32 + quad * 8];
                    f4v acc = {0.f, 0.f, 0.f, 0.f};
                    acc = __builtin_amdgcn_mfma_f32_16x16x32_bf16(a0s, u0, acc, 0, 0, 0);
                    acc = __builtin_amdgcn_mfma_f32_16x16x32_bf16(a1s, u1, acc, 0, 0, 0);
                    const int kk = hl * 8 + (cl & 7) + (cl >> 3) * 16;
                    #pragma unroll
                    for (int j = 0; j < 4; ++j) {
                        float v = acc[j] * 0.125f;
                        float mx = v;
                        mx = fmaxf(mx, __shfl_xor(mx, 1));
                        mx = fmaxf(mx, __shfl_xor(mx, 2));
                        mx = fmaxf(mx, __shfl_xor(mx, 4));
                        float ex = __expf(v - mx);
                        float sm = ex;
                        sm += __shfl_xor(sm, 1);
                        sm += __shfl_xor(sm, 2);
                        sm += __shfl_xor(sm, 4);
                        float aw = valid ? ex * __builtin_amdgcn_rcpf(sm) : 0.f;
                        sAblk[p][quad * 4 + j][kk] = f2bf(aw);
                    }
                }
            }

            // ---- PV (same-wave sAblk dependency: no barrier needed) ----
            {
                const int p = wv;
                bf8v a0p = *(const bf8v*)&sAblk[p][cl][quad * 8];
                #pragma unroll
                for (int nt = 0; nt < 4; ++nt) {
                    bf8v bz = *(const bf8v*)&sZt[p][nt * 16 + cl][quad * 8];
                    accO[nt] = __builtin_amdgcn_mfma_f32_16x16x32_bf16(a0p, bz, accO[nt], 0, 0, 0);
                }
            }
            // write next-l UE rows before the half-1 barrier (this wave's own
            // 16 rows; its scores-reads of those rows are complete, and all
            // other waves only read their own rows in scores).  Merges the old
            // end-of-loop barrier into this one: 4 barriers/l instead of 5.
            if (half == 1 && li + 1 < LCH_) store_ue();
            BARRIER();
        }

        // ---- +lin_b, LayerNorm per row over 64 cols, accumulate over l ----
        {
            float x[16];
            #pragma unroll
            for (int nt = 0; nt < 4; ++nt)
                #pragma unroll
                for (int j = 0; j < 4; ++j)
                    x[nt * 4 + j] = accO[nt][j] + sLinb[li][nt * 16 + cl];
            #pragma unroll
            for (int j = 0; j < 4; ++j) {
                float s = x[j] + x[4 + j] + x[8 + j] + x[12 + j];
                #pragma unroll
                for (int m = 1; m < 16; m <<= 1) s += __shfl_xor(s, m);
                float mean = s * (1.f / 64.f);
                float q = 0.f;
                #pragma unroll
                for (int nt = 0; nt < 4; ++nt) { float d = x[nt * 4 + j] - mean; q += d * d; }
                #pragma unroll
                for (int m = 1; m < 16; m <<= 1) q += __shfl_xor(q, m);
                float rst = rsqrtf(q * (1.f / 64.f) + LN_EPS);
                #pragma unroll
                for (int nt = 0; nt < 4; ++nt) {
                    int col = nt * 16 + cl;
                    lnacc[nt * 4 + j] += (x[nt * 4 + j] - mean) * rst * sLng[col] + sLnb[col];
                }
            }
        }
    }

    #pragma unroll
    for (int j = 0; j < 4; ++j) {
        const int row = wv * 16 + quad * 4 + j;
        const int b = b0 + (row >> 3), f = row & 7;
        #pragma unroll
        for (int nt = 0; nt < 4; ++nt)
            atomicAdd(&ubs_acc[(size_t)b * 512 + f * 64 + nt * 16 + cl], lnacc[nt * 4 + j]);
    }
}

// ---------------------------------------------------------------------------
// gemm core: C[m0..+16][n0..+64] += LDS-A . Bw^T + bias.  4 waves, 16 col/wave.
// ---------------------------------------------------------------------------
__device__ __forceinline__ void gemm_from_lds(
    const unsigned short* sA, int lda,
    const unsigned short* __restrict__ Bw, const float* __restrict__ bias,
    float* __restrict__ Cd, int K, int N, int n0w, int m0,
    int quad, int cl)
{
    f4v acc0 = {0.f, 0.f, 0.f, 0.f};
    f4v acc1 = {0.f, 0.f, 0.f, 0.f};
    const unsigned short* arow = sA + cl * lda + quad * 8;
    const unsigned short* brow = Bw + (size_t)(n0w + cl) * K + quad * 8;
    int k0 = 0;
    for (; k0 + 64 <= K; k0 += 64) {
        bf8v a0 = *(const bf8v*)(arow + k0);
        bf8v b0 = *(const bf8v*)(brow + k0);
        bf8v a1 = *(const bf8v*)(arow + k0 + 32);
        bf8v b1 = *(const bf8v*)(brow + k0 + 32);
        acc0 = __builtin_amdgcn_mfma_f32_16x16x32_bf16(a0, b0, acc0, 0, 0, 0);
        acc1 = __builtin_amdgcn_mfma_f32_16x16x32_bf16(a1, b1, acc1, 0, 0, 0);
    }
    if (k0 < K) {
        bf8v a = *(const bf8v*)(arow + k0);
        bf8v b = *(const bf8v*)(brow + k0);
        acc0 = __builtin_amdgcn_mfma_f32_16x16x32_bf16(a, b, acc0, 0, 0, 0);
    }
    float bv = bias[n0w + cl];
    #pragma unroll
    for (int j = 0; j < 4; ++j)
        Cd[(size_t)(m0 + quad * 4 + j) * N + n0w + cl] = acc0[j] + acc1[j] + bv;
}

// ---------------------------------------------------------------------------
// LN-from-C into LDS bf16 (per-block, 16 rows, N cols).  row = t>>4, sub = t&15.
// ---------------------------------------------------------------------------
__device__ __forceinline__ void ln_rows_to_lds(
    const float* __restrict__ Cd, int N, int m0,
    const float* __restrict__ g, const float* __restrict__ bb,
    unsigned short* sH, int lda, int t, float invN)
{
    const int r = t >> 4, sub = t & 15;
    const float* crow = Cd + (size_t)(m0 + r) * N;
    float s = 0.f, s2 = 0.f;
    for (int j = sub * 4; j < N; j += 64) {
        float4 x = *(const float4*)(crow + j);
        s  += x.x + x.y + x.z + x.w;
        s2 += x.x * x.x + x.y * x.y + x.z * x.z + x.w * x.w;
    }
    #pragma unroll
    for (int m = 1; m < 16; m <<= 1) { s += __shfl_xor(s, m); s2 += __shfl_xor(s2, m); }
    const float mean = s * invN;
    const float var  = s2 * invN - mean * mean;
    const float rst  = rsqrtf(fmaxf(var, 0.f) + LN_EPS);
    for (int j = sub * 4; j < N; j += 64) {
        float4 x = *(const float4*)(crow + j);
        ushort4 o;
        o.x = f2bf(fmaxf((x.x - mean) * rst * g[j]     + bb[j],     0.f));
        o.y = f2bf(fmaxf((x.y - mean) * rst * g[j + 1] + bb[j + 1], 0.f));
        o.z = f2bf(fmaxf((x.z - mean) * rst * g[j + 2] + bb[j + 2], 0.f));
        o.w = f2bf(fmaxf((x.w - mean) * rst * g[j + 3] + bb[j + 3], 0.f));
        *(ushort4*)&sH[r * lda + j] = o;
    }
}

// ---------------------------------------------------------------------------
// Kernel G1: X-build (LDS) + gemm1 -> C1 f32.  grid (16 n x 16 m) = 256 blocks.
// ---------------------------------------------------------------------------
#define XLD 1320
__global__ __launch_bounds__(256) void gemm1x_kernel(
    const float* __restrict__ ubs_acc,
    const int* __restrict__ target_ad, const int* __restrict__ profile_feature,
    const float* __restrict__ context,
    const float* __restrict__ item_tables, const float* __restrict__ profile_tables,
    const unsigned short* __restrict__ Wt1, const float* __restrict__ b1,
    float* __restrict__ C1)
{
    __shared__ __align__(16) unsigned short sX[16][XLD];
    const int t = threadIdx.x;
    const int wv = t >> 6, lane = t & 63, quad = lane >> 4, cl = lane & 15;
    const int m0 = (blockIdx.x >> 4) * 16;
    const int n0w = (blockIdx.x & 15) * 64 + wv * 16;

    {
        const int r = t >> 4, sub = t & 15;
        const int gb = m0 + r;
        #pragma unroll
        for (int k = 0; k < 21; ++k) {
            int cc = sub * 4 + k * 64;
            if (cc >= TOWER_IN_) break;
            float4 x;
            if (cc < 512) {
                x = *(const float4*)(ubs_acc + (size_t)gb * 512 + cc);
                x.x = fmaxf(x.x * 0.01f, 0.f); x.y = fmaxf(x.y * 0.01f, 0.f);
                x.z = fmaxf(x.z * 0.01f, 0.f); x.w = fmaxf(x.w * 0.01f, 0.f);
            } else if (cc < 1024) {
                int f = (cc - 512) >> 6, e = (cc - 512) & 63;
                x = *(const float4*)(item_tables + ((size_t)f * V_ + target_ad[gb * 8 + f]) * 64 + e);
            } else if (cc < 1280) {
                int pp = (cc - 1024) >> 6, e = (cc - 1024) & 63;
                x = *(const float4*)(profile_tables + ((size_t)pp * V_ + profile_feature[gb * 4 + pp]) * 64 + e);
            } else {
                x = *(const float4*)(context + (size_t)gb * 32 + (cc - 1280));
            }
            ushort4 o;
            o.x = f2bf(x.x); o.y = f2bf(x.y); o.z = f2bf(x.z); o.w = f2bf(x.w);
            *(ushort4*)&sX[r][cc] = o;
        }
    }
    __syncthreads();
    gemm_from_lds(&sX[0][0], XLD, Wt1, b1, C1, 1312, 1024, n0w, m0, quad, cl);
}

// ---------------------------------------------------------------------------
// Kernel G2: LN1(C1)+ReLU (LDS) + gemm2 -> C2 f32.  grid (8 n x 16 m) = 128.
// ---------------------------------------------------------------------------
#define H1LD 1032
__global__ __launch_bounds__(256) void gemm2f_kernel(
    const float* __restrict__ C1, const float* __restrict__ g1,
    const float* __restrict__ bb1,
    const unsigned short* __restrict__ Wt2, const float* __restrict__ b2,
    float* __restrict__ C2)
{
    __shared__ __align__(16) unsigned short sH[16][H1LD];
    const int t = threadIdx.x;
    const int wv = t >> 6, lane = t & 63, quad = lane >> 4, cl = lane & 15;
    const int m0 = (blockIdx.x >> 3) * 16;
    const int n0w = (blockIdx.x & 7) * 64 + wv * 16;

    ln_rows_to_lds(C1, 1024, m0, g1, bb1, &sH[0][0], H1LD, t, 1.f / 1024.f);
    __syncthreads();
    gemm_from_lds(&sH[0][0], H1LD, Wt2, b2, C2, 1024, 512, n0w, m0, quad, cl);
}

// ---------------------------------------------------------------------------
// Kernel G3: LN2(C2)+ReLU (LDS) + gemm3 (full 256-col rows) + LN3 + ReLU +
// dot(w4) + sigmoid -> out.  grid = 16 blocks (16 rows each), 256 threads.
// ---------------------------------------------------------------------------
#define H2LD 520
__global__ __launch_bounds__(256) void gemm3f_kernel(
    const float* __restrict__ C2, const float* __restrict__ g2,
    const float* __restrict__ bb2,
    const unsigned short* __restrict__ Wt3, const float* __restrict__ b3,
    const float* __restrict__ g3, const float* __restrict__ bb3,
    const float* __restrict__ w4, const float* __restrict__ b4,
    float* __restrict__ out)
{
    __shared__ __align__(16) unsigned short sH[16][H2LD];
    __shared__ float sS[4][16], sQ[4][16], sP[4][16];
    const int t = threadIdx.x;
    const int wv = t >> 6, lane = t & 63, quad = lane >> 4, cl = lane & 15;
    const int m0 = blockIdx.x * 16;

    ln_rows_to_lds(C2, 512, m0, g2, bb2, &sH[0][0], H2LD, t, 1.f / 512.f);
    __syncthreads();

    f4v acc[4];
    #pragma unroll
    for (int nt = 0; nt < 4; ++nt) acc[nt] = {0.f, 0.f, 0.f, 0.f};
    for (int k0 = 0; k0 < 512; k0 += 32) {
        bf8v a = *(const bf8v*)&sH[cl][k0 + quad * 8];
        #pragma unroll
        for (int nt = 0; nt < 4; ++nt) {
            const int col0 = wv * 64 + nt * 16;
            bf8v b = *(const bf8v*)(Wt3 + (size_t)(col0 + cl) * 512 + k0 + quad * 8);
            acc[nt] = __builtin_amdgcn_mfma_f32_16x16x32_bf16(a, b, acc[nt], 0, 0, 0);
        }
    }
    #pragma unroll
    for (int nt = 0; nt < 4; ++nt) {
        float bv = b3[wv * 64 + nt * 16 + cl];
        #pragma unroll
        for (int j = 0; j < 4; ++j) acc[nt][j] += bv;
    }

    #pragma unroll
    for (int j = 0; j < 4; ++j) {
        float s = acc[0][j] + acc[1][j] + acc[2][j] + acc[3][j];
        float q = acc[0][j]*acc[0][j] + acc[1][j]*acc[1][j] + acc[2][j]*acc[2][j] + acc[3][j]*acc[3][j];
        #pragma unroll
        for (int m = 1; m < 16; m <<= 1) { s += __shfl_xor(s, m); q += __shfl_xor(q, m); }
        if (cl == 0) { sS[wv][quad * 4 + j] = s; sQ[wv][quad * 4 + j] = q; }
    }
    __syncthreads();
    float meanr[4], rstdr[4];
    #pragma unroll
    for (int j = 0; j < 4; ++j) {
        const int row = quad * 4 + j;
        float s = sS[0][row] + sS[1][row] + sS[2][row] + sS[3][row];
        float q = sQ[0][row] + sQ[1][row] + sQ[2][row] + sQ[3][row];
        float mean = s * (1.f / 256.f);
        float var  = q * (1.f / 256.f) - mean * mean;
        meanr[j] = mean;
        rstdr[j] = rsqrtf(fmaxf(var, 0.f) + LN_EPS);
    }

    #pragma unroll
    for (int j = 0; j < 4; ++j) {
        float p = 0.f;
        #pragma unroll
        for (int nt = 0; nt < 4; ++nt) {
            const int col = wv * 64 + nt * 16 + cl;
            float h = fmaxf((acc[nt][j] - meanr[j]) * rstdr[j] * g3[col] + bb3[col], 0.f);
            p += h * w4[col];
        }
        #pragma unroll
        for (int m = 1; m < 16; m <<= 1) p += __shfl_xor(p, m);
        if (cl == 0) sP[wv][quad * 4 + j] = p;
    }
    __syncthreads();
    if (t < 16) {
        float p = sP[0][t] + sP[1][t] + sP[2][t] + sP[3][t];
        out[m0 + t] = 1.f / (1.f + expf(-(p + b4[0])));
    }
}

// ---------------------------------------------------------------------------
extern "C" void kernel_launch(void* const* d_in, const int* in_sizes, int n_in,
                              void* d_out, int out_size, void* d_ws, size_t ws_size,
                              hipStream_t stream)
{
    (void)in_sizes; (void)n_in; (void)out_size; (void)ws_size;
    const int*   target_ad       = (const int*)d_in[0];
    const int*   ubs_feature     = (const int*)d_in[1];
    const int*   profile_feature = (const int*)d_in[2];
    const float* context         = (const float*)d_in[3];
    const float* item_tables     = (const float*)d_in[4];
    const float* profile_tables  = (const float*)d_in[5];
    const float* q_w   = (const float*)d_in[6];
    const float* k_w   = (const float*)d_in[7];
    const float* v_w   = (const float*)d_in[8];
    const float* lin_w = (const float*)d_in[9];
    const float* lin_b = (const float*)d_in[10];
    const float* ln_g  = (const float*)d_in[11];
    const float* ln_b  = (const float*)d_in[12];
    const float* t_w1  = (const float*)d_in[13];
    const float* t_b1  = (const float*)d_in[14];
    const float* t_g1  = (const float*)d_in[15];
    const float* t_bb1 = (const float*)d_in[16];
    const float* t_w2  = (const float*)d_in[17];
    const float* t_b2  = (const float*)d_in[18];
    const float* t_g2  = (const float*)d_in[19];
    const float* t_bb2 = (const float*)d_in[20];
    const float* t_w3  = (const float*)d_in[21];
    const float* t_b3  = (const float*)d_in[22];
    const float* t_g3  = (const float*)d_in[23];
    const float* t_bb3 = (const float*)d_in[24];
    const float* t_w4  = (const float*)d_in[25];
    const float* t_b4  = (const float*)d_in[26];

    char* ws = (char*)d_ws;
    unsigned short* wsMT = (unsigned short*)(ws);              //  3,276,800
    unsigned short* wsWT = (unsigned short*)(ws +  3276800);   //  3,276,800
    float* ubs_acc       = (float*)         (ws +  6553600);   //    524,288
    unsigned short* Wt1  = (unsigned short*)(ws +  7077888);   //  2,686,976
    unsigned short* Wt2  = (unsigned short*)(ws +  9764864);   //  1,048,576
    unsigned short* Wt3  = (unsigned short*)(ws + 10813440);   //    262,144
    float*          C1   = (float*)         (ws + 11075584);   //  1,048,576
    float*          C2   = (float*)         (ws + 12124160);   //    524,288 (end 12,648,448)

    pre_kernel<<<528, 256, 0, stream>>>(q_w, k_w, v_w, lin_w, wsMT, wsWT, ubs_acc);
    attn_kernel<<<800 + 1952, 256, 0, stream>>>(ubs_feature, item_tables, wsMT, wsWT,
                                                lin_b, ln_g, ln_b, ubs_acc,
                                                t_w1, t_w2, t_w3, Wt1, Wt2, Wt3);
    gemm1x_kernel<<<256, 256, 0, stream>>>(ubs_acc, target_ad, profile_feature, context,
                                           item_tables, profile_tables, Wt1, t_b1, C1);
    gemm2f_kernel<<<128, 256, 0, stream>>>(C1, t_g1, t_bb1, Wt2, t_b2, C2);
    gemm3f_kernel<<<16, 256, 0, stream>>>(C2, t_g2, t_bb2, Wt3, t_b3,
                                          t_g3, t_bb3, t_w4, t_b4, (float*)d_out);
}

// Round 11
// 242.672 us; speedup vs baseline: 1.1971x; 1.0786x over previous
//
#include <hip/hip_runtime.h>
#include <hip/hip_bf16.h>

#define B_ 256
#define L_ 100
#define F_ 8
#define P_ 4
#define E_ 64
#define H_ 4
#define D_ 64
#define C_ 32
#define V_ 10000
#define TOWER_IN_ 1312
#define LN_EPS 0.001f
#define LCH_ 5    // l's per attention block (5 => 640 blocks: 1 full residency round)
#define NCH_ 20   // number of l-chunks
#define ZK_ 40    // padded k-stride for sZt (80B: 16B-aligned, conflict-free)
#define ATTN_BLKS_ (NCH_ * 32)   // 640

typedef __attribute__((ext_vector_type(8))) short bf8v;           // 8 bf16 (4 VGPRs)
typedef __attribute__((ext_vector_type(8))) unsigned short us8;   // 8 u16
typedef __attribute__((ext_vector_type(4))) float f4v;            // 4 f32 acc

__device__ __forceinline__ unsigned short f2bf(float x) {
    __hip_bfloat16 h = __float2bfloat16(x);
    return __builtin_bit_cast(unsigned short, h);
}

// raw barrier: LDS-drain + s_barrier, NO vmcnt drain (prefetch loads stay in flight)
#define BARRIER() do { \
    asm volatile("s_waitcnt lgkmcnt(0)" ::: "memory"); \
    __builtin_amdgcn_s_barrier(); \
    asm volatile("" ::: "memory"); \
} while (0)

// ---------------------------------------------------------------------------
// Kernel PRE: precomp (register-tiled f32) + ubs_acc zero.
// ---------------------------------------------------------------------------
__global__ __launch_bounds__(256) void pre_kernel(
    const float* __restrict__ q_w, const float* __restrict__ k_w,
    const float* __restrict__ v_w, const float* __restrict__ lin_w,
    unsigned short* __restrict__ wsMT, unsigned short* __restrict__ wsWT,
    float* __restrict__ ubs_acc)
{
    __shared__ float sA[64][68];
    __shared__ float sB[64][68];
    const int t = threadIdx.x;
    const int bx = blockIdx.x;

    if (bx >= 400) {
        const int bi = bx - 400;                   // 128 blocks x 1024 floats
        float4 z = {0.f, 0.f, 0.f, 0.f};
        *(float4*)(ubs_acc + (size_t)bi * 1024 + t * 4) = z;
        return;
    }

    const int l = bx >> 2;
    const int h = bx & 3;
    const size_t obase = (size_t)(l * 4 + h) * 4096;
    const int te = t & 15, to = t >> 4;

    for (int i = 0; i < 16; ++i) {
        int idx = t + i * 256;
        int e = idx >> 6, d = idx & 63;
        sA[e][d] = q_w[(l * 64 + e) * 256 + h * 64 + d];
        sB[e][d] = k_w[(l * 64 + e) * 256 + h * 64 + d];
    }
    __syncthreads();
    {
        float acc[4][4];
        #pragma unroll
        for (int i = 0; i < 4; ++i)
            #pragma unroll
            for (int j = 0; j < 4; ++j) acc[i][j] = 0.f;
        for (int d0 = 0; d0 < 64; d0 += 4) {
            float4 a4[4], b4[4];
            #pragma unroll
            for (int i = 0; i < 4; ++i) a4[i] = *(const float4*)&sA[te + 16 * i][d0];
            #pragma unroll
            for (int j = 0; j < 4; ++j) b4[j] = *(const float4*)&sB[to + 16 * j][d0];
            #pragma unroll
            for (int i = 0; i < 4; ++i)
                #pragma unroll
                for (int j = 0; j < 4; ++j) {
                    acc[i][j] += a4[i].x * b4[j].x;
                    acc[i][j] += a4[i].y * b4[j].y;
                    acc[i][j] += a4[i].z * b4[j].z;
                    acc[i][j] += a4[i].w * b4[j].w;
                }
        }
        #pragma unroll
        for (int j = 0; j < 4; ++j)
            #pragma unroll
            for (int i = 0; i < 4; ++i)
                wsMT[obase + (to + 16 * j) * 64 + (te + 16 * i)] = f2bf(acc[i][j]);
    }
    __syncthreads();

    for (int i = 0; i < 16; ++i) {
        int idx = t + i * 256;
        int e = idx >> 6, d = idx & 63;
        sA[e][d] = v_w[(l * 64 + e) * 256 + h * 64 + d];
        int oo = idx & 63, dd = idx >> 6;
        sB[oo][dd] = lin_w[l * 16384 + (h * 64 + dd) * 64 + oo];
    }
    __syncthreads();
    {
        float acc[4][4];
        #pragma unroll
        for (int i = 0; i < 4; ++i)
            #pragma unroll
            for (int j = 0; j < 4; ++j) acc[i][j] = 0.f;
        for (int d0 = 0; d0 < 64; d0 += 4) {
            float4 a4[4], b4[4];
            #pragma unroll
            for (int i = 0; i < 4; ++i) a4[i] = *(const float4*)&sA[te + 16 * i][d0];
            #pragma unroll
            for (int j = 0; j < 4; ++j) b4[j] = *(const float4*)&sB[to + 16 * j][d0];
            #pragma unroll
            for (int i = 0; i < 4; ++i)
                #pragma unroll
                for (int j = 0; j < 4; ++j) {
                    acc[i][j] += a4[i].x * b4[j].x;
                    acc[i][j] += a4[i].y * b4[j].y;
                    acc[i][j] += a4[i].z * b4[j].z;
                    acc[i][j] += a4[i].w * b4[j].w;
                }
        }
        #pragma unroll
        for (int j = 0; j < 4; ++j)
            #pragma unroll
            for (int i = 0; i < 4; ++i)
                wsWT[obase + (to + 16 * j) * 64 + (te + 16 * i)] = f2bf(acc[i][j]);
    }
}

// ---------------------------------------------------------------------------
// Kernel A: fused attention (blocks < 640) + tower weight prep (blocks >= 640).
// 640 attn blocks @ 3/CU: ALL co-resident (<= 768 slots) -> exactly 1
// residency round (R10 lesson: 800 blocks = 768 + 32 stragglers = 2 rounds).
// Free slots (768-640) let prep blocks overlap attn from the start.
// ---------------------------------------------------------------------------
__global__ __launch_bounds__(256, 3) void attn_kernel(
    const int* __restrict__ ubs_feature, const float* __restrict__ item_tables,
    const unsigned short* __restrict__ wsMT, const unsigned short* __restrict__ wsWT,
    const float* __restrict__ lin_b, const float* __restrict__ ln_g,
    const float* __restrict__ ln_b, float* __restrict__ ubs_acc,
    const float* __restrict__ w1, const float* __restrict__ w2,
    const float* __restrict__ w3,
    unsigned short* __restrict__ Wt1, unsigned short* __restrict__ Wt2,
    unsigned short* __restrict__ Wt3)
{
    __shared__ __align__(16) unsigned short sUE[64][72];       // rows=b_loc*8+f
    __shared__ __align__(16) unsigned short sT[64][136];       // cols=hl*64+e'
    __shared__ __align__(16) unsigned short sZt[4][64][ZK_];   // [pair][e][k] (k<32 used)
    __shared__ __align__(16) unsigned short sAblk[4][16][32];  // [pair][r][k]
    __shared__ float sLng[64], sLnb[64], sLinb[LCH_][64];

    const int t = threadIdx.x;

    if (blockIdx.x >= ATTN_BLKS_) {
        // ---------------- prep (weight transpose) ----------------
        float (*tile)[33] = (float (*)[33])sT;   // 32x33 f32 fits in sT region
        int bi = blockIdx.x - ATTN_BLKS_;
        const float* src; unsigned short* dst; int K, N, tk, tn;
        if (bi < 1312)      { src = w1; dst = Wt1; K = 1312; N = 1024; tk = bi / 32;  tn = bi % 32; }
        else if (bi < 1824) { int i = bi - 1312; src = w2; dst = Wt2; K = 1024; N = 512; tk = i / 16; tn = i % 16; }
        else                { int i = bi - 1824; src = w3; dst = Wt3; K = 512;  N = 256; tk = i / 8;  tn = i % 8; }
        const int k0 = tk * 32, n0 = tn * 32;
        const int rr = t >> 5, cc = t & 31;
        #pragma unroll
        for (int i = 0; i < 4; ++i) {
            int r = rr * 4 + i;
            tile[r][cc] = src[(size_t)(k0 + r) * N + n0 + cc];
        }
        __syncthreads();
        #pragma unroll
        for (int i = 0; i < 4; ++i) {
            int r = rr * 4 + i;
            dst[(size_t)(n0 + r) * K + k0 + cc] = f2bf(tile[cc][r]);
        }
        return;
    }

    const int c = blockIdx.x >> 5;            // l-chunk 0..19
    const int b0 = (blockIdx.x & 31) * 8;
    const int wv = t >> 6, lane = t & 63, quad = lane >> 4, cl = lane & 15;
    const int role = wv >> 1, hlw = wv & 1;

    const int grow = wv * 16 + (lane >> 2);   // row in [0,64) = b_loc*8 + f
    const int gseg = lane & 3;                // 16-float segment
    const int gb = b0 + (grow >> 3), gf = grow & 7;

    if (t < 64) { sLng[t] = ln_g[t]; sLnb[t] = ln_b[t]; }
    if (t >= 64 && t < 128) {
        #pragma unroll
        for (int li = 0; li < LCH_; ++li)
            sLinb[li][t - 64] = lin_b[(c * LCH_ + li) * 64 + (t - 64)];
    }

    int vidx[LCH_];
    #pragma unroll
    for (int li = 0; li < LCH_; ++li)
        vidx[li] = ubs_feature[(gb * L_ + c * LCH_ + li) * F_ + gf];

    float4 pf[4];
    bf8v bfrag[4][2];

    auto load_bfrag = [&](int lh) {   // lh = l*4 + half*2 + hlw
        const unsigned short* Bsrc = (role == 0 ? wsMT : wsWT) + ((size_t)lh * 4096);
        #pragma unroll
        for (int nt = 0; nt < 4; ++nt)
            #pragma unroll
            for (int k2 = 0; k2 < 2; ++k2)
                bfrag[nt][k2] = *(const bf8v*)(Bsrc + (nt * 16 + cl) * 64 + k2 * 32 + quad * 8);
    };
    auto load_pf = [&](int li) {
        const float* srcp = item_tables + ((size_t)gf * V_ + vidx[li]) * 64 + gseg * 16;
        #pragma unroll
        for (int j = 0; j < 4; ++j) pf[j] = ((const float4*)srcp)[j];
    };
    auto store_ue = [&]() {
        us8 u0, u1;
        u0[0] = f2bf(pf[0].x); u0[1] = f2bf(pf[0].y); u0[2] = f2bf(pf[0].z); u0[3] = f2bf(pf[0].w);
        u0[4] = f2bf(pf[1].x); u0[5] = f2bf(pf[1].y); u0[6] = f2bf(pf[1].z); u0[7] = f2bf(pf[1].w);
        u1[0] = f2bf(pf[2].x); u1[1] = f2bf(pf[2].y); u1[2] = f2bf(pf[2].z); u1[3] = f2bf(pf[2].w);
        u1[4] = f2bf(pf[3].x); u1[5] = f2bf(pf[3].y); u1[6] = f2bf(pf[3].z); u1[7] = f2bf(pf[3].w);
        *(us8*)&sUE[grow][gseg * 16]     = u0;
        *(us8*)&sUE[grow][gseg * 16 + 8] = u1;
    };

    load_pf(0);
    load_bfrag((c * LCH_) * 4 + hlw);
    store_ue();
    BARRIER();

    float lnacc[16];
    #pragma unroll
    for (int i = 0; i < 16; ++i) lnacc[i] = 0.f;

    for (int li = 0; li < LCH_; ++li) {
        const int l = c * LCH_ + li;

        if (li + 1 < LCH_) load_pf(li + 1);

        f4v accO[4];
        #pragma unroll
        for (int nt = 0; nt < 4; ++nt) accO[nt] = {0.f, 0.f, 0.f, 0.f};

        #pragma unroll
        for (int half = 0; half < 2; ++half) {
            // ---- phase A: waves 0,1 -> T; waves 2,3 -> Zt ----
            #pragma unroll
            for (int m = 0; m < 4; ++m) {
                bf8v a0 = *(const bf8v*)&sUE[m * 16 + cl][quad * 8];
                bf8v a1 = *(const bf8v*)&sUE[m * 16 + cl][32 + quad * 8];
                #pragma unroll
                for (int nt = 0; nt < 4; ++nt) {
                    f4v acc = {0.f, 0.f, 0.f, 0.f};
                    acc = __builtin_amdgcn_mfma_f32_16x16x32_bf16(a0, bfrag[nt][0], acc, 0, 0, 0);
                    acc = __builtin_amdgcn_mfma_f32_16x16x32_bf16(a1, bfrag[nt][1], acc, 0, 0, 0);
                    if (role == 0) {
                        #pragma unroll
                        for (int j = 0; j < 4; ++j)
                            sT[m * 16 + quad * 4 + j][hlw * 64 + nt * 16 + cl] = f2bf(acc[j]);
                    } else {
                        ushort4 zp;
                        zp.x = f2bf(acc[0]); zp.y = f2bf(acc[1]);
                        zp.z = f2bf(acc[2]); zp.w = f2bf(acc[3]);
                        const int k0 = (quad >> 1) * 16 + hlw * 8 + (quad & 1) * 4;
                        *(ushort4*)&sZt[m][nt * 16 + cl][k0] = zp;
                    }
                }
            }
            if (half == 0)            load_bfrag(l * 4 + 2 + hlw);
            else if (li + 1 < LCH_)   load_bfrag((l + 1) * 4 + hlw);
            BARRIER();

            // ---- scores + softmax + Ablk (wave = pair) ----
            {
                const int p = wv;
                const bool valid = (cl >> 3) == (quad >> 1);
                bf8v u0 = *(const bf8v*)&sUE[p * 16 + cl][quad * 8];
                bf8v u1 = *(const bf8v*)&sUE[p * 16 + cl][32 + quad * 8];
                #pragma unroll
                for (int hl = 0; hl < 2; ++hl) {
                    bf8v a0s = *(const bf8v*)&sT[p * 16 + cl][hl * 64 + quad * 8];
                    bf8v a1s = *(const bf8v*)&sT[p * 16 + cl][hl * 64 + 32 + quad * 8];
                    f4v acc = {0.f, 0.f, 0.f, 0.f};
                    acc = __builtin_amdgcn_mfma_f32_16x16x32_bf16(a0s, u0, acc, 0, 0, 0);
                    acc = __builtin_amdgcn_mfma_f32_16x16x32_bf16(a1s, u1, acc, 0, 0, 0);
                    const int kk = hl * 8 + (cl & 7) + (cl >> 3) * 16;
                    #pragma unroll
                    for (int j = 0; j < 4; ++j) {
                        float v = acc[j] * 0.125f;
                        float mx = v;
                        mx = fmaxf(mx, __shfl_xor(mx, 1));
                        mx = fmaxf(mx, __shfl_xor(mx, 2));
                        mx = fmaxf(mx, __shfl_xor(mx, 4));
                        float ex = __expf(v - mx);
                        float sm = ex;
                        sm += __shfl_xor(sm, 1);
                        sm += __shfl_xor(sm, 2);
                        sm += __shfl_xor(sm, 4);
                        float aw = valid ? ex * __builtin_amdgcn_rcpf(sm) : 0.f;
                        sAblk[p][quad * 4 + j][kk] = f2bf(aw);
                    }
                }
            }

            // ---- PV (same-wave sAblk dependency: no barrier needed) ----
            {
                const int p = wv;
                bf8v a0p = *(const bf8v*)&sAblk[p][cl][quad * 8];
                #pragma unroll
                for (int nt = 0; nt < 4; ++nt) {
                    bf8v bz = *(const bf8v*)&sZt[p][nt * 16 + cl][quad * 8];
                    accO[nt] = __builtin_amdgcn_mfma_f32_16x16x32_bf16(a0p, bz, accO[nt], 0, 0, 0);
                }
            }
            // write next-l UE rows before the half-1 barrier (wave's own rows;
            // all waves' reads of sUE for this l are complete).  4 barriers/l.
            if (half == 1 && li + 1 < LCH_) store_ue();
            BARRIER();
        }

        // ---- +lin_b, LayerNorm per row over 64 cols, accumulate over l ----
        {
            float x[16];
            #pragma unroll
            for (int nt = 0; nt < 4; ++nt)
                #pragma unroll
                for (int j = 0; j < 4; ++j)
                    x[nt * 4 + j] = accO[nt][j] + sLinb[li][nt * 16 + cl];
            #pragma unroll
            for (int j = 0; j < 4; ++j) {
                float s = x[j] + x[4 + j] + x[8 + j] + x[12 + j];
                #pragma unroll
                for (int m = 1; m < 16; m <<= 1) s += __shfl_xor(s, m);
                float mean = s * (1.f / 64.f);
                float q = 0.f;
                #pragma unroll
                for (int nt = 0; nt < 4; ++nt) { float d = x[nt * 4 + j] - mean; q += d * d; }
                #pragma unroll
                for (int m = 1; m < 16; m <<= 1) q += __shfl_xor(q, m);
                float rst = rsqrtf(q * (1.f / 64.f) + LN_EPS);
                #pragma unroll
                for (int nt = 0; nt < 4; ++nt) {
                    int col = nt * 16 + cl;
                    lnacc[nt * 4 + j] += (x[nt * 4 + j] - mean) * rst * sLng[col] + sLnb[col];
                }
            }
        }
    }

    #pragma unroll
    for (int j = 0; j < 4; ++j) {
        const int row = wv * 16 + quad * 4 + j;
        const int b = b0 + (row >> 3), f = row & 7;
        #pragma unroll
        for (int nt = 0; nt < 4; ++nt)
            atomicAdd(&ubs_acc[(size_t)b * 512 + f * 64 + nt * 16 + cl], lnacc[nt * 4 + j]);
    }
}

// ---------------------------------------------------------------------------
// gemm core: C[m0..+16][n0..+64] += LDS-A . Bw^T + bias.  4 waves, 16 col/wave.
// ---------------------------------------------------------------------------
__device__ __forceinline__ void gemm_from_lds(
    const unsigned short* sA, int lda,
    const unsigned short* __restrict__ Bw, const float* __restrict__ bias,
    float* __restrict__ Cd, int K, int N, int n0w, int m0,
    int quad, int cl)
{
    f4v acc0 = {0.f, 0.f, 0.f, 0.f};
    f4v acc1 = {0.f, 0.f, 0.f, 0.f};
    const unsigned short* arow = sA + cl * lda + quad * 8;
    const unsigned short* brow = Bw + (size_t)(n0w + cl) * K + quad * 8;
    int k0 = 0;
    for (; k0 + 64 <= K; k0 += 64) {
        bf8v a0 = *(const bf8v*)(arow + k0);
        bf8v b0 = *(const bf8v*)(brow + k0);
        bf8v a1 = *(const bf8v*)(arow + k0 + 32);
        bf8v b1 = *(const bf8v*)(brow + k0 + 32);
        acc0 = __builtin_amdgcn_mfma_f32_16x16x32_bf16(a0, b0, acc0, 0, 0, 0);
        acc1 = __builtin_amdgcn_mfma_f32_16x16x32_bf16(a1, b1, acc1, 0, 0, 0);
    }
    if (k0 < K) {
        bf8v a = *(const bf8v*)(arow + k0);
        bf8v b = *(const bf8v*)(brow + k0);
        acc0 = __builtin_amdgcn_mfma_f32_16x16x32_bf16(a, b, acc0, 0, 0, 0);
    }
    float bv = bias[n0w + cl];
    #pragma unroll
    for (int j = 0; j < 4; ++j)
        Cd[(size_t)(m0 + quad * 4 + j) * N + n0w + cl] = acc0[j] + acc1[j] + bv;
}

// ---------------------------------------------------------------------------
// LN-from-C into LDS bf16 (per-block, 16 rows, N cols).  row = t>>4, sub = t&15.
// ---------------------------------------------------------------------------
__device__ __forceinline__ void ln_rows_to_lds(
    const float* __restrict__ Cd, int N, int m0,
    const float* __restrict__ g, const float* __restrict__ bb,
    unsigned short* sH, int lda, int t, float invN)
{
    const int r = t >> 4, sub = t & 15;
    const float* crow = Cd + (size_t)(m0 + r) * N;
    float s = 0.f, s2 = 0.f;
    for (int j = sub * 4; j < N; j += 64) {
        float4 x = *(const float4*)(crow + j);
        s  += x.x + x.y + x.z + x.w;
        s2 += x.x * x.x + x.y * x.y + x.z * x.z + x.w * x.w;
    }
    #pragma unroll
    for (int m = 1; m < 16; m <<= 1) { s += __shfl_xor(s, m); s2 += __shfl_xor(s2, m); }
    const float mean = s * invN;
    const float var  = s2 * invN - mean * mean;
    const float rst  = rsqrtf(fmaxf(var, 0.f) + LN_EPS);
    for (int j = sub * 4; j < N; j += 64) {
        float4 x = *(const float4*)(crow + j);
        ushort4 o;
        o.x = f2bf(fmaxf((x.x - mean) * rst * g[j]     + bb[j],     0.f));
        o.y = f2bf(fmaxf((x.y - mean) * rst * g[j + 1] + bb[j + 1], 0.f));
        o.z = f2bf(fmaxf((x.z - mean) * rst * g[j + 2] + bb[j + 2], 0.f));
        o.w = f2bf(fmaxf((x.w - mean) * rst * g[j + 3] + bb[j + 3], 0.f));
        *(ushort4*)&sH[r * lda + j] = o;
    }
}

// ---------------------------------------------------------------------------
// Kernel G1: X-build (LDS) + gemm1 -> C1 f32.  grid (16 n x 16 m) = 256 blocks.
// ---------------------------------------------------------------------------
#define XLD 1320
__global__ __launch_bounds__(256) void gemm1x_kernel(
    const float* __restrict__ ubs_acc,
    const int* __restrict__ target_ad, const int* __restrict__ profile_feature,
    const float* __restrict__ context,
    const float* __restrict__ item_tables, const float* __restrict__ profile_tables,
    const unsigned short* __restrict__ Wt1, const float* __restrict__ b1,
    float* __restrict__ C1)
{
    __shared__ __align__(16) unsigned short sX[16][XLD];
    const int t = threadIdx.x;
    const int wv = t >> 6, lane = t & 63, quad = lane >> 4, cl = lane & 15;
    const int m0 = (blockIdx.x >> 4) * 16;
    const int n0w = (blockIdx.x & 15) * 64 + wv * 16;

    {
        const int r = t >> 4, sub = t & 15;
        const int gb = m0 + r;
        #pragma unroll
        for (int k = 0; k < 21; ++k) {
            int cc = sub * 4 + k * 64;
            if (cc >= TOWER_IN_) break;
            float4 x;
            if (cc < 512) {
                x = *(const float4*)(ubs_acc + (size_t)gb * 512 + cc);
                x.x = fmaxf(x.x * 0.01f, 0.f); x.y = fmaxf(x.y * 0.01f, 0.f);
                x.z = fmaxf(x.z * 0.01f, 0.f); x.w = fmaxf(x.w * 0.01f, 0.f);
            } else if (cc < 1024) {
                int f = (cc - 512) >> 6, e = (cc - 512) & 63;
                x = *(const float4*)(item_tables + ((size_t)f * V_ + target_ad[gb * 8 + f]) * 64 + e);
            } else if (cc < 1280) {
                int pp = (cc - 1024) >> 6, e = (cc - 1024) & 63;
                x = *(const float4*)(profile_tables + ((size_t)pp * V_ + profile_feature[gb * 4 + pp]) * 64 + e);
            } else {
                x = *(const float4*)(context + (size_t)gb * 32 + (cc - 1280));
            }
            ushort4 o;
            o.x = f2bf(x.x); o.y = f2bf(x.y); o.z = f2bf(x.z); o.w = f2bf(x.w);
            *(ushort4*)&sX[r][cc] = o;
        }
    }
    __syncthreads();
    gemm_from_lds(&sX[0][0], XLD, Wt1, b1, C1, 1312, 1024, n0w, m0, quad, cl);
}

// ---------------------------------------------------------------------------
// Kernel G2: LN1(C1)+ReLU (LDS) + gemm2 -> C2 f32.  grid (8 n x 16 m) = 128.
// ---------------------------------------------------------------------------
#define H1LD 1032
__global__ __launch_bounds__(256) void gemm2f_kernel(
    const float* __restrict__ C1, const float* __restrict__ g1,
    const float* __restrict__ bb1,
    const unsigned short* __restrict__ Wt2, const float* __restrict__ b2,
    float* __restrict__ C2)
{
    __shared__ __align__(16) unsigned short sH[16][H1LD];
    const int t = threadIdx.x;
    const int wv = t >> 6, lane = t & 63, quad = lane >> 4, cl = lane & 15;
    const int m0 = (blockIdx.x >> 3) * 16;
    const int n0w = (blockIdx.x & 7) * 64 + wv * 16;

    ln_rows_to_lds(C1, 1024, m0, g1, bb1, &sH[0][0], H1LD, t, 1.f / 1024.f);
    __syncthreads();
    gemm_from_lds(&sH[0][0], H1LD, Wt2, b2, C2, 1024, 512, n0w, m0, quad, cl);
}

// ---------------------------------------------------------------------------
// Kernel G3: LN2(C2)+ReLU (LDS) + gemm3 (full 256-col rows) + LN3 + ReLU +
// dot(w4) + sigmoid -> out.  grid = 16 blocks (16 rows each), 256 threads.
// ---------------------------------------------------------------------------
#define H2LD 520
__global__ __launch_bounds__(256) void gemm3f_kernel(
    const float* __restrict__ C2, const float* __restrict__ g2,
    const float* __restrict__ bb2,
    const unsigned short* __restrict__ Wt3, const float* __restrict__ b3,
    const float* __restrict__ g3, const float* __restrict__ bb3,
    const float* __restrict__ w4, const float* __restrict__ b4,
    float* __restrict__ out)
{
    __shared__ __align__(16) unsigned short sH[16][H2LD];
    __shared__ float sS[4][16], sQ[4][16], sP[4][16];
    const int t = threadIdx.x;
    const int wv = t >> 6, lane = t & 63, quad = lane >> 4, cl = lane & 15;
    const int m0 = blockIdx.x * 16;

    ln_rows_to_lds(C2, 512, m0, g2, bb2, &sH[0][0], H2LD, t, 1.f / 512.f);
    __syncthreads();

    f4v acc[4];
    #pragma unroll
    for (int nt = 0; nt < 4; ++nt) acc[nt] = {0.f, 0.f, 0.f, 0.f};
    for (int k0 = 0; k0 < 512; k0 += 32) {
        bf8v a = *(const bf8v*)&sH[cl][k0 + quad * 8];
        #pragma unroll
        for (int nt = 0; nt < 4; ++nt) {
            const int col0 = wv * 64 + nt * 16;
            bf8v b = *(const bf8v*)(Wt3 + (size_t)(col0 + cl) * 512 + k0 + quad * 8);
            acc[nt] = __builtin_amdgcn_mfma_f32_16x16x32_bf16(a, b, acc[nt], 0, 0, 0);
        }
    }
    #pragma unroll
    for (int nt = 0; nt < 4; ++nt) {
        float bv = b3[wv * 64 + nt * 16 + cl];
        #pragma unroll
        for (int j = 0; j < 4; ++j) acc[nt][j] += bv;
    }

    #pragma unroll
    for (int j = 0; j < 4; ++j) {
        float s = acc[0][j] + acc[1][j] + acc[2][j] + acc[3][j];
        float q = acc[0][j]*acc[0][j] + acc[1][j]*acc[1][j] + acc[2][j]*acc[2][j] + acc[3][j]*acc[3][j];
        #pragma unroll
        for (int m = 1; m < 16; m <<= 1) { s += __shfl_xor(s, m); q += __shfl_xor(q, m); }
        if (cl == 0) { sS[wv][quad * 4 + j] = s; sQ[wv][quad * 4 + j] = q; }
    }
    __syncthreads();
    float meanr[4], rstdr[4];
    #pragma unroll
    for (int j = 0; j < 4; ++j) {
        const int row = quad * 4 + j;
        float s = sS[0][row] + sS[1][row] + sS[2][row] + sS[3][row];
        float q = sQ[0][row] + sQ[1][row] + sQ[2][row] + sQ[3][row];
        float mean = s * (1.f / 256.f);
        float var  = q * (1.f / 256.f) - mean * mean;
        meanr[j] = mean;
        rstdr[j] = rsqrtf(fmaxf(var, 0.f) + LN_EPS);
    }

    #pragma unroll
    for (int j = 0; j < 4; ++j) {
        float p = 0.f;
        #pragma unroll
        for (int nt = 0; nt < 4; ++nt) {
            const int col = wv * 64 + nt * 16 + cl;
            float h = fmaxf((acc[nt][j] - meanr[j]) * rstdr[j] * g3[col] + bb3[col], 0.f);
            p += h * w4[col];
        }
        #pragma unroll
        for (int m = 1; m < 16; m <<= 1) p += __shfl_xor(p, m);
        if (cl == 0) sP[wv][quad * 4 + j] = p;
    }
    __syncthreads();
    if (t < 16) {
        float p = sP[0][t] + sP[1][t] + sP[2][t] + sP[3][t];
        out[m0 + t] = 1.f / (1.f + expf(-(p + b4[0])));
    }
}

// ---------------------------------------------------------------------------
extern "C" void kernel_launch(void* const* d_in, const int* in_sizes, int n_in,
                              void* d_out, int out_size, void* d_ws, size_t ws_size,
                              hipStream_t stream)
{
    (void)in_sizes; (void)n_in; (void)out_size; (void)ws_size;
    const int*   target_ad       = (const int*)d_in[0];
    const int*   ubs_feature     = (const int*)d_in[1];
    const int*   profile_feature = (const int*)d_in[2];
    const float* context         = (const float*)d_in[3];
    const float* item_tables     = (const float*)d_in[4];
    const float* profile_tables  = (const float*)d_in[5];
    const float* q_w   = (const float*)d_in[6];
    const float* k_w   = (const float*)d_in[7];
    const float* v_w   = (const float*)d_in[8];
    const float* lin_w = (const float*)d_in[9];
    const float* lin_b = (const float*)d_in[10];
    const float* ln_g  = (const float*)d_in[11];
    const float* ln_b  = (const float*)d_in[12];
    const float* t_w1  = (const float*)d_in[13];
    const float* t_b1  = (const float*)d_in[14];
    const float* t_g1  = (const float*)d_in[15];
    const float* t_bb1 = (const float*)d_in[16];
    const float* t_w2  = (const float*)d_in[17];
    const float* t_b2  = (const float*)d_in[18];
    const float* t_g2  = (const float*)d_in[19];
    const float* t_bb2 = (const float*)d_in[20];
    const float* t_w3  = (const float*)d_in[21];
    const float* t_b3  = (const float*)d_in[22];
    const float* t_g3  = (const float*)d_in[23];
    const float* t_bb3 = (const float*)d_in[24];
    const float* t_w4  = (const float*)d_in[25];
    const float* t_b4  = (const float*)d_in[26];

    char* ws = (char*)d_ws;
    unsigned short* wsMT = (unsigned short*)(ws);              //  3,276,800
    unsigned short* wsWT = (unsigned short*)(ws +  3276800);   //  3,276,800
    float* ubs_acc       = (float*)         (ws +  6553600);   //    524,288
    unsigned short* Wt1  = (unsigned short*)(ws +  7077888);   //  2,686,976
    unsigned short* Wt2  = (unsigned short*)(ws +  9764864);   //  1,048,576
    unsigned short* Wt3  = (unsigned short*)(ws + 10813440);   //    262,144
    float*          C1   = (float*)         (ws + 11075584);   //  1,048,576
    float*          C2   = (float*)         (ws + 12124160);   //    524,288 (end 12,648,448)

    pre_kernel<<<528, 256, 0, stream>>>(q_w, k_w, v_w, lin_w, wsMT, wsWT, ubs_acc);
    attn_kernel<<<ATTN_BLKS_ + 1952, 256, 0, stream>>>(ubs_feature, item_tables, wsMT, wsWT,
                                                       lin_b, ln_g, ln_b, ubs_acc,
                                                       t_w1, t_w2, t_w3, Wt1, Wt2, Wt3);
    gemm1x_kernel<<<256, 256, 0, stream>>>(ubs_acc, target_ad, profile_feature, context,
                                           item_tables, profile_tables, Wt1, t_b1, C1);
    gemm2f_kernel<<<128, 256, 0, stream>>>(C1, t_g1, t_bb1, Wt2, t_b2, C2);
    gemm3f_kernel<<<16, 256, 0, stream>>>(C2, t_g2, t_bb2, Wt3, t_b3,
                                          t_g3, t_bb3, t_w4, t_b4, (float*)d_out);
}

// Round 12
// 242.275 us; speedup vs baseline: 1.1991x; 1.0016x over previous
//
#include <hip/hip_runtime.h>
#include <hip/hip_bf16.h>

#define B_ 256
#define L_ 100
#define F_ 8
#define P_ 4
#define E_ 64
#define H_ 4
#define D_ 64
#define C_ 32
#define V_ 10000
#define TOWER_IN_ 1312
#define LN_EPS 0.001f
#define LCHMAX_ 5  // max l's per attention block (chunks 0-3: 5 l's, 4-23: 4 l's)
#define NCH_ 24    // number of l-chunks (4*5 + 20*4 = 100 l's)
#define ZK_ 40     // padded k-stride for sZt (80B: 16B-aligned, conflict-free)
#define ATTN_BLKS_ (NCH_ * 32)   // 768 = exactly 3 blocks/CU on 256 CUs

typedef __attribute__((ext_vector_type(8))) short bf8v;           // 8 bf16 (4 VGPRs)
typedef __attribute__((ext_vector_type(8))) unsigned short us8;   // 8 u16
typedef __attribute__((ext_vector_type(4))) float f4v;            // 4 f32 acc

__device__ __forceinline__ unsigned short f2bf(float x) {
    __hip_bfloat16 h = __float2bfloat16(x);
    return __builtin_bit_cast(unsigned short, h);
}

// raw barrier: LDS-drain + s_barrier, NO vmcnt drain (prefetch loads stay in flight)
#define BARRIER() do { \
    asm volatile("s_waitcnt lgkmcnt(0)" ::: "memory"); \
    __builtin_amdgcn_s_barrier(); \
    asm volatile("" ::: "memory"); \
} while (0)

// ---------------------------------------------------------------------------
// Kernel PRE: precomp (register-tiled f32) + ubs_acc zero.
// ---------------------------------------------------------------------------
__global__ __launch_bounds__(256) void pre_kernel(
    const float* __restrict__ q_w, const float* __restrict__ k_w,
    const float* __restrict__ v_w, const float* __restrict__ lin_w,
    unsigned short* __restrict__ wsMT, unsigned short* __restrict__ wsWT,
    float* __restrict__ ubs_acc)
{
    __shared__ float sA[64][68];
    __shared__ float sB[64][68];
    const int t = threadIdx.x;
    const int bx = blockIdx.x;

    if (bx >= 400) {
        const int bi = bx - 400;                   // 128 blocks x 1024 floats
        float4 z = {0.f, 0.f, 0.f, 0.f};
        *(float4*)(ubs_acc + (size_t)bi * 1024 + t * 4) = z;
        return;
    }

    const int l = bx >> 2;
    const int h = bx & 3;
    const size_t obase = (size_t)(l * 4 + h) * 4096;
    const int te = t & 15, to = t >> 4;

    for (int i = 0; i < 16; ++i) {
        int idx = t + i * 256;
        int e = idx >> 6, d = idx & 63;
        sA[e][d] = q_w[(l * 64 + e) * 256 + h * 64 + d];
        sB[e][d] = k_w[(l * 64 + e) * 256 + h * 64 + d];
    }
    __syncthreads();
    {
        float acc[4][4];
        #pragma unroll
        for (int i = 0; i < 4; ++i)
            #pragma unroll
            for (int j = 0; j < 4; ++j) acc[i][j] = 0.f;
        for (int d0 = 0; d0 < 64; d0 += 4) {
            float4 a4[4], b4[4];
            #pragma unroll
            for (int i = 0; i < 4; ++i) a4[i] = *(const float4*)&sA[te + 16 * i][d0];
            #pragma unroll
            for (int j = 0; j < 4; ++j) b4[j] = *(const float4*)&sB[to + 16 * j][d0];
            #pragma unroll
            for (int i = 0; i < 4; ++i)
                #pragma unroll
                for (int j = 0; j < 4; ++j) {
                    acc[i][j] += a4[i].x * b4[j].x;
                    acc[i][j] += a4[i].y * b4[j].y;
                    acc[i][j] += a4[i].z * b4[j].z;
                    acc[i][j] += a4[i].w * b4[j].w;
                }
        }
        #pragma unroll
        for (int j = 0; j < 4; ++j)
            #pragma unroll
            for (int i = 0; i < 4; ++i)
                wsMT[obase + (to + 16 * j) * 64 + (te + 16 * i)] = f2bf(acc[i][j]);
    }
    __syncthreads();

    for (int i = 0; i < 16; ++i) {
        int idx = t + i * 256;
        int e = idx >> 6, d = idx & 63;
        sA[e][d] = v_w[(l * 64 + e) * 256 + h * 64 + d];
        int oo = idx & 63, dd = idx >> 6;
        sB[oo][dd] = lin_w[l * 16384 + (h * 64 + dd) * 64 + oo];
    }
    __syncthreads();
    {
        float acc[4][4];
        #pragma unroll
        for (int i = 0; i < 4; ++i)
            #pragma unroll
            for (int j = 0; j < 4; ++j) acc[i][j] = 0.f;
        for (int d0 = 0; d0 < 64; d0 += 4) {
            float4 a4[4], b4[4];
            #pragma unroll
            for (int i = 0; i < 4; ++i) a4[i] = *(const float4*)&sA[te + 16 * i][d0];
            #pragma unroll
            for (int j = 0; j < 4; ++j) b4[j] = *(const float4*)&sB[to + 16 * j][d0];
            #pragma unroll
            for (int i = 0; i < 4; ++i)
                #pragma unroll
                for (int j = 0; j < 4; ++j) {
                    acc[i][j] += a4[i].x * b4[j].x;
                    acc[i][j] += a4[i].y * b4[j].y;
                    acc[i][j] += a4[i].z * b4[j].z;
                    acc[i][j] += a4[i].w * b4[j].w;
                }
        }
        #pragma unroll
        for (int j = 0; j < 4; ++j)
            #pragma unroll
            for (int i = 0; i < 4; ++i)
                wsWT[obase + (to + 16 * j) * 64 + (te + 16 * i)] = f2bf(acc[i][j]);
    }
}

// ---------------------------------------------------------------------------
// Kernel A: fused attention (blocks < 768) + tower weight prep (blocks >= 768).
// 768 attn blocks = EXACTLY 3/CU (full residency, 1 round, uniform load).
// Chunks 0-3 cover 5 l's, chunks 4-23 cover 4 l's (total 100): worst-CU work
// drops 15 -> ~12.5 l (R11 lesson: finish time = most-loaded CU).
// ---------------------------------------------------------------------------
__global__ __launch_bounds__(256, 3) void attn_kernel(
    const int* __restrict__ ubs_feature, const float* __restrict__ item_tables,
    const unsigned short* __restrict__ wsMT, const unsigned short* __restrict__ wsWT,
    const float* __restrict__ lin_b, const float* __restrict__ ln_g,
    const float* __restrict__ ln_b, float* __restrict__ ubs_acc,
    const float* __restrict__ w1, const float* __restrict__ w2,
    const float* __restrict__ w3,
    unsigned short* __restrict__ Wt1, unsigned short* __restrict__ Wt2,
    unsigned short* __restrict__ Wt3)
{
    __shared__ __align__(16) unsigned short sUE[64][72];       // rows=b_loc*8+f
    __shared__ __align__(16) unsigned short sT[64][136];       // cols=hl*64+e'
    __shared__ __align__(16) unsigned short sZt[4][64][ZK_];   // [pair][e][k] (k<32 used)
    __shared__ __align__(16) unsigned short sAblk[4][16][32];  // [pair][r][k]
    __shared__ float sLng[64], sLnb[64], sLinb[LCHMAX_][64];

    const int t = threadIdx.x;

    if (blockIdx.x >= ATTN_BLKS_) {
        // ---------------- prep (weight transpose) ----------------
        float (*tile)[33] = (float (*)[33])sT;   // 32x33 f32 fits in sT region
        int bi = blockIdx.x - ATTN_BLKS_;
        const float* src; unsigned short* dst; int K, N, tk, tn;
        if (bi < 1312)      { src = w1; dst = Wt1; K = 1312; N = 1024; tk = bi / 32;  tn = bi % 32; }
        else if (bi < 1824) { int i = bi - 1312; src = w2; dst = Wt2; K = 1024; N = 512; tk = i / 16; tn = i % 16; }
        else                { int i = bi - 1824; src = w3; dst = Wt3; K = 512;  N = 256; tk = i / 8;  tn = i % 8; }
        const int k0 = tk * 32, n0 = tn * 32;
        const int rr = t >> 5, cc = t & 31;
        #pragma unroll
        for (int i = 0; i < 4; ++i) {
            int r = rr * 4 + i;
            tile[r][cc] = src[(size_t)(k0 + r) * N + n0 + cc];
        }
        __syncthreads();
        #pragma unroll
        for (int i = 0; i < 4; ++i) {
            int r = rr * 4 + i;
            dst[(size_t)(n0 + r) * K + k0 + cc] = f2bf(tile[cc][r]);
        }
        return;
    }

    const int c = blockIdx.x >> 5;            // l-chunk 0..23
    const int lch   = (c < 4) ? 5 : 4;        // chunks 0-3: 5 l's; 4-23: 4 l's
    const int lbase = (c < 4) ? c * 5 : 20 + (c - 4) * 4;
    const int b0 = (blockIdx.x & 31) * 8;
    const int wv = t >> 6, lane = t & 63, quad = lane >> 4, cl = lane & 15;
    const int role = wv >> 1, hlw = wv & 1;

    const int grow = wv * 16 + (lane >> 2);   // row in [0,64) = b_loc*8 + f
    const int gseg = lane & 3;                // 16-float segment
    const int gb = b0 + (grow >> 3), gf = grow & 7;

    if (t < 64) { sLng[t] = ln_g[t]; sLnb[t] = ln_b[t]; }
    if (t >= 64 && t < 128) {
        for (int li = 0; li < lch; ++li)
            sLinb[li][t - 64] = lin_b[(lbase + li) * 64 + (t - 64)];
    }

    int vidx[LCHMAX_];
    for (int li = 0; li < lch; ++li)
        vidx[li] = ubs_feature[(gb * L_ + lbase + li) * F_ + gf];

    float4 pf[4];
    bf8v bfrag[4][2];

    auto load_bfrag = [&](int lh) {   // lh = l*4 + half*2 + hlw
        const unsigned short* Bsrc = (role == 0 ? wsMT : wsWT) + ((size_t)lh * 4096);
        #pragma unroll
        for (int nt = 0; nt < 4; ++nt)
            #pragma unroll
            for (int k2 = 0; k2 < 2; ++k2)
                bfrag[nt][k2] = *(const bf8v*)(Bsrc + (nt * 16 + cl) * 64 + k2 * 32 + quad * 8);
    };
    auto load_pf = [&](int li) {
        const float* srcp = item_tables + ((size_t)gf * V_ + vidx[li]) * 64 + gseg * 16;
        #pragma unroll
        for (int j = 0; j < 4; ++j) pf[j] = ((const float4*)srcp)[j];
    };
    auto store_ue = [&]() {
        us8 u0, u1;
        u0[0] = f2bf(pf[0].x); u0[1] = f2bf(pf[0].y); u0[2] = f2bf(pf[0].z); u0[3] = f2bf(pf[0].w);
        u0[4] = f2bf(pf[1].x); u0[5] = f2bf(pf[1].y); u0[6] = f2bf(pf[1].z); u0[7] = f2bf(pf[1].w);
        u1[0] = f2bf(pf[2].x); u1[1] = f2bf(pf[2].y); u1[2] = f2bf(pf[2].z); u1[3] = f2bf(pf[2].w);
        u1[4] = f2bf(pf[3].x); u1[5] = f2bf(pf[3].y); u1[6] = f2bf(pf[3].z); u1[7] = f2bf(pf[3].w);
        *(us8*)&sUE[grow][gseg * 16]     = u0;
        *(us8*)&sUE[grow][gseg * 16 + 8] = u1;
    };

    load_pf(0);
    load_bfrag(lbase * 4 + hlw);
    store_ue();
    BARRIER();

    float lnacc[16];
    #pragma unroll
    for (int i = 0; i < 16; ++i) lnacc[i] = 0.f;

    for (int li = 0; li < lch; ++li) {
        const int l = lbase + li;

        if (li + 1 < lch) load_pf(li + 1);

        f4v accO[4];
        #pragma unroll
        for (int nt = 0; nt < 4; ++nt) accO[nt] = {0.f, 0.f, 0.f, 0.f};

        #pragma unroll
        for (int half = 0; half < 2; ++half) {
            // ---- phase A: waves 0,1 -> T; waves 2,3 -> Zt ----
            #pragma unroll
            for (int m = 0; m < 4; ++m) {
                bf8v a0 = *(const bf8v*)&sUE[m * 16 + cl][quad * 8];
                bf8v a1 = *(const bf8v*)&sUE[m * 16 + cl][32 + quad * 8];
                #pragma unroll
                for (int nt = 0; nt < 4; ++nt) {
                    f4v acc = {0.f, 0.f, 0.f, 0.f};
                    acc = __builtin_amdgcn_mfma_f32_16x16x32_bf16(a0, bfrag[nt][0], acc, 0, 0, 0);
                    acc = __builtin_amdgcn_mfma_f32_16x16x32_bf16(a1, bfrag[nt][1], acc, 0, 0, 0);
                    if (role == 0) {
                        #pragma unroll
                        for (int j = 0; j < 4; ++j)
                            sT[m * 16 + quad * 4 + j][hlw * 64 + nt * 16 + cl] = f2bf(acc[j]);
                    } else {
                        ushort4 zp;
                        zp.x = f2bf(acc[0]); zp.y = f2bf(acc[1]);
                        zp.z = f2bf(acc[2]); zp.w = f2bf(acc[3]);
                        const int k0 = (quad >> 1) * 16 + hlw * 8 + (quad & 1) * 4;
                        *(ushort4*)&sZt[m][nt * 16 + cl][k0] = zp;
                    }
                }
            }
            if (half == 0)          load_bfrag(l * 4 + 2 + hlw);
            else if (li + 1 < lch)  load_bfrag((l + 1) * 4 + hlw);
            BARRIER();

            // ---- scores + softmax + Ablk (wave = pair) ----
            {
                const int p = wv;
                const bool valid = (cl >> 3) == (quad >> 1);
                bf8v u0 = *(const bf8v*)&sUE[p * 16 + cl][quad * 8];
                bf8v u1 = *(const bf8v*)&sUE[p * 16 + cl][32 + quad * 8];
                #pragma unroll
                for (int hl = 0; hl < 2; ++hl) {
                    bf8v a0s = *(const bf8v*)&sT[p * 16 + cl][hl * 64 + quad * 8];
                    bf8v a1s = *(const bf8v*)&sT[p * 16 + cl][hl * 64 + 32 + quad * 8];
                    f4v acc = {0.f, 0.f, 0.f, 0.f};
                    acc = __builtin_amdgcn_mfma_f32_16x16x32_bf16(a0s, u0, acc, 0, 0, 0);
                    acc = __builtin_amdgcn_mfma_f32_16x16x32_bf16(a1s, u1, acc, 0, 0, 0);
                    const int kk = hl * 8 + (cl & 7) + (cl >> 3) * 16;
                    #pragma unroll
                    for (int j = 0; j < 4; ++j) {
                        float v = acc[j] * 0.125f;
                        float mx = v;
                        mx = fmaxf(mx, __shfl_xor(mx, 1));
                        mx = fmaxf(mx, __shfl_xor(mx, 2));
                        mx = fmaxf(mx, __shfl_xor(mx, 4));
                        float ex = __expf(v - mx);
                        float sm = ex;
                        sm += __shfl_xor(sm, 1);
                        sm += __shfl_xor(sm, 2);
                        sm += __shfl_xor(sm, 4);
                        float aw = valid ? ex * __builtin_amdgcn_rcpf(sm) : 0.f;
                        sAblk[p][quad * 4 + j][kk] = f2bf(aw);
                    }
                }
            }

            // ---- PV (same-wave sAblk dependency: no barrier needed) ----
            {
                const int p = wv;
                bf8v a0p = *(const bf8v*)&sAblk[p][cl][quad * 8];
                #pragma unroll
                for (int nt = 0; nt < 4; ++nt) {
                    bf8v bz = *(const bf8v*)&sZt[p][nt * 16 + cl][quad * 8];
                    accO[nt] = __builtin_amdgcn_mfma_f32_16x16x32_bf16(a0p, bz, accO[nt], 0, 0, 0);
                }
            }
            // write next-l UE rows before the half-1 barrier (wave's own rows;
            // all waves' reads of sUE for this l are complete).  4 barriers/l.
            if (half == 1 && li + 1 < lch) store_ue();
            BARRIER();
        }

        // ---- +lin_b, LayerNorm per row over 64 cols, accumulate over l ----
        {
            float x[16];
            #pragma unroll
            for (int nt = 0; nt < 4; ++nt)
                #pragma unroll
                for (int j = 0; j < 4; ++j)
                    x[nt * 4 + j] = accO[nt][j] + sLinb[li][nt * 16 + cl];
            #pragma unroll
            for (int j = 0; j < 4; ++j) {
                float s = x[j] + x[4 + j] + x[8 + j] + x[12 + j];
                #pragma unroll
                for (int m = 1; m < 16; m <<= 1) s += __shfl_xor(s, m);
                float mean = s * (1.f / 64.f);
                float q = 0.f;
                #pragma unroll
                for (int nt = 0; nt < 4; ++nt) { float d = x[nt * 4 + j] - mean; q += d * d; }
                #pragma unroll
                for (int m = 1; m < 16; m <<= 1) q += __shfl_xor(q, m);
                float rst = rsqrtf(q * (1.f / 64.f) + LN_EPS);
                #pragma unroll
                for (int nt = 0; nt < 4; ++nt) {
                    int col = nt * 16 + cl;
                    lnacc[nt * 4 + j] += (x[nt * 4 + j] - mean) * rst * sLng[col] + sLnb[col];
                }
            }
        }
    }

    #pragma unroll
    for (int j = 0; j < 4; ++j) {
        const int row = wv * 16 + quad * 4 + j;
        const int b = b0 + (row >> 3), f = row & 7;
        #pragma unroll
        for (int nt = 0; nt < 4; ++nt)
            atomicAdd(&ubs_acc[(size_t)b * 512 + f * 64 + nt * 16 + cl], lnacc[nt * 4 + j]);
    }
}

// ---------------------------------------------------------------------------
// gemm core: C[m0..+16][n0..+64] += LDS-A . Bw^T + bias.  4 waves, 16 col/wave.
// ---------------------------------------------------------------------------
__device__ __forceinline__ void gemm_from_lds(
    const unsigned short* sA, int lda,
    const unsigned short* __restrict__ Bw, const float* __restrict__ bias,
    float* __restrict__ Cd, int K, int N, int n0w, int m0,
    int quad, int cl)
{
    f4v acc0 = {0.f, 0.f, 0.f, 0.f};
    f4v acc1 = {0.f, 0.f, 0.f, 0.f};
    const unsigned short* arow = sA + cl * lda + quad * 8;
    const unsigned short* brow = Bw + (size_t)(n0w + cl) * K + quad * 8;
    int k0 = 0;
    for (; k0 + 64 <= K; k0 += 64) {
        bf8v a0 = *(const bf8v*)(arow + k0);
        bf8v b0 = *(const bf8v*)(brow + k0);
        bf8v a1 = *(const bf8v*)(arow + k0 + 32);
        bf8v b1 = *(const bf8v*)(brow + k0 + 32);
        acc0 = __builtin_amdgcn_mfma_f32_16x16x32_bf16(a0, b0, acc0, 0, 0, 0);
        acc1 = __builtin_amdgcn_mfma_f32_16x16x32_bf16(a1, b1, acc1, 0, 0, 0);
    }
    if (k0 < K) {
        bf8v a = *(const bf8v*)(arow + k0);
        bf8v b = *(const bf8v*)(brow + k0);
        acc0 = __builtin_amdgcn_mfma_f32_16x16x32_bf16(a, b, acc0, 0, 0, 0);
    }
    float bv = bias[n0w + cl];
    #pragma unroll
    for (int j = 0; j < 4; ++j)
        Cd[(size_t)(m0 + quad * 4 + j) * N + n0w + cl] = acc0[j] + acc1[j] + bv;
}

// ---------------------------------------------------------------------------
// LN-from-C into LDS bf16 (per-block, 16 rows, N cols).  row = t>>4, sub = t&15.
// ---------------------------------------------------------------------------
__device__ __forceinline__ void ln_rows_to_lds(
    const float* __restrict__ Cd, int N, int m0,
    const float* __restrict__ g, const float* __restrict__ bb,
    unsigned short* sH, int lda, int t, float invN)
{
    const int r = t >> 4, sub = t & 15;
    const float* crow = Cd + (size_t)(m0 + r) * N;
    float s = 0.f, s2 = 0.f;
    for (int j = sub * 4; j < N; j += 64) {
        float4 x = *(const float4*)(crow + j);
        s  += x.x + x.y + x.z + x.w;
        s2 += x.x * x.x + x.y * x.y + x.z * x.z + x.w * x.w;
    }
    #pragma unroll
    for (int m = 1; m < 16; m <<= 1) { s += __shfl_xor(s, m); s2 += __shfl_xor(s2, m); }
    const float mean = s * invN;
    const float var  = s2 * invN - mean * mean;
    const float rst  = rsqrtf(fmaxf(var, 0.f) + LN_EPS);
    for (int j = sub * 4; j < N; j += 64) {
        float4 x = *(const float4*)(crow + j);
        ushort4 o;
        o.x = f2bf(fmaxf((x.x - mean) * rst * g[j]     + bb[j],     0.f));
        o.y = f2bf(fmaxf((x.y - mean) * rst * g[j + 1] + bb[j + 1], 0.f));
        o.z = f2bf(fmaxf((x.z - mean) * rst * g[j + 2] + bb[j + 2], 0.f));
        o.w = f2bf(fmaxf((x.w - mean) * rst * g[j + 3] + bb[j + 3], 0.f));
        *(ushort4*)&sH[r * lda + j] = o;
    }
}

// ---------------------------------------------------------------------------
// Kernel G1: X-build (LDS) + gemm1 -> C1 f32.  grid (16 n x 16 m) = 256 blocks.
// ---------------------------------------------------------------------------
#define XLD 1320
__global__ __launch_bounds__(256) void gemm1x_kernel(
    const float* __restrict__ ubs_acc,
    const int* __restrict__ target_ad, const int* __restrict__ profile_feature,
    const float* __restrict__ context,
    const float* __restrict__ item_tables, const float* __restrict__ profile_tables,
    const unsigned short* __restrict__ Wt1, const float* __restrict__ b1,
    float* __restrict__ C1)
{
    __shared__ __align__(16) unsigned short sX[16][XLD];
    const int t = threadIdx.x;
    const int wv = t >> 6, lane = t & 63, quad = lane >> 4, cl = lane & 15;
    const int m0 = (blockIdx.x >> 4) * 16;
    const int n0w = (blockIdx.x & 15) * 64 + wv * 16;

    {
        const int r = t >> 4, sub = t & 15;
        const int gb = m0 + r;
        #pragma unroll
        for (int k = 0; k < 21; ++k) {
            int cc = sub * 4 + k * 64;
            if (cc >= TOWER_IN_) break;
            float4 x;
            if (cc < 512) {
                x = *(const float4*)(ubs_acc + (size_t)gb * 512 + cc);
                x.x = fmaxf(x.x * 0.01f, 0.f); x.y = fmaxf(x.y * 0.01f, 0.f);
                x.z = fmaxf(x.z * 0.01f, 0.f); x.w = fmaxf(x.w * 0.01f, 0.f);
            } else if (cc < 1024) {
                int f = (cc - 512) >> 6, e = (cc - 512) & 63;
                x = *(const float4*)(item_tables + ((size_t)f * V_ + target_ad[gb * 8 + f]) * 64 + e);
            } else if (cc < 1280) {
                int pp = (cc - 1024) >> 6, e = (cc - 1024) & 63;
                x = *(const float4*)(profile_tables + ((size_t)pp * V_ + profile_feature[gb * 4 + pp]) * 64 + e);
            } else {
                x = *(const float4*)(context + (size_t)gb * 32 + (cc - 1280));
            }
            ushort4 o;
            o.x = f2bf(x.x); o.y = f2bf(x.y); o.z = f2bf(x.z); o.w = f2bf(x.w);
            *(ushort4*)&sX[r][cc] = o;
        }
    }
    __syncthreads();
    gemm_from_lds(&sX[0][0], XLD, Wt1, b1, C1, 1312, 1024, n0w, m0, quad, cl);
}

// ---------------------------------------------------------------------------
// Kernel G2: LN1(C1)+ReLU (LDS) + gemm2 -> C2 f32.  grid (8 n x 16 m) = 128.
// ---------------------------------------------------------------------------
#define H1LD 1032
__global__ __launch_bounds__(256) void gemm2f_kernel(
    const float* __restrict__ C1, const float* __restrict__ g1,
    const float* __restrict__ bb1,
    const unsigned short* __restrict__ Wt2, const float* __restrict__ b2,
    float* __restrict__ C2)
{
    __shared__ __align__(16) unsigned short sH[16][H1LD];
    const int t = threadIdx.x;
    const int wv = t >> 6, lane = t & 63, quad = lane >> 4, cl = lane & 15;
    const int m0 = (blockIdx.x >> 3) * 16;
    const int n0w = (blockIdx.x & 7) * 64 + wv * 16;

    ln_rows_to_lds(C1, 1024, m0, g1, bb1, &sH[0][0], H1LD, t, 1.f / 1024.f);
    __syncthreads();
    gemm_from_lds(&sH[0][0], H1LD, Wt2, b2, C2, 1024, 512, n0w, m0, quad, cl);
}

// ---------------------------------------------------------------------------
// Kernel G3: LN2(C2)+ReLU (LDS) + gemm3 (full 256-col rows) + LN3 + ReLU +
// dot(w4) + sigmoid -> out.  grid = 16 blocks (16 rows each), 256 threads.
// ---------------------------------------------------------------------------
#define H2LD 520
__global__ __launch_bounds__(256) void gemm3f_kernel(
    const float* __restrict__ C2, const float* __restrict__ g2,
    const float* __restrict__ bb2,
    const unsigned short* __restrict__ Wt3, const float* __restrict__ b3,
    const float* __restrict__ g3, const float* __restrict__ bb3,
    const float* __restrict__ w4, const float* __restrict__ b4,
    float* __restrict__ out)
{
    __shared__ __align__(16) unsigned short sH[16][H2LD];
    __shared__ float sS[4][16], sQ[4][16], sP[4][16];
    const int t = threadIdx.x;
    const int wv = t >> 6, lane = t & 63, quad = lane >> 4, cl = lane & 15;
    const int m0 = blockIdx.x * 16;

    ln_rows_to_lds(C2, 512, m0, g2, bb2, &sH[0][0], H2LD, t, 1.f / 512.f);
    __syncthreads();

    f4v acc[4];
    #pragma unroll
    for (int nt = 0; nt < 4; ++nt) acc[nt] = {0.f, 0.f, 0.f, 0.f};
    for (int k0 = 0; k0 < 512; k0 += 32) {
        bf8v a = *(const bf8v*)&sH[cl][k0 + quad * 8];
        #pragma unroll
        for (int nt = 0; nt < 4; ++nt) {
            const int col0 = wv * 64 + nt * 16;
            bf8v b = *(const bf8v*)(Wt3 + (size_t)(col0 + cl) * 512 + k0 + quad * 8);
            acc[nt] = __builtin_amdgcn_mfma_f32_16x16x32_bf16(a, b, acc[nt], 0, 0, 0);
        }
    }
    #pragma unroll
    for (int nt = 0; nt < 4; ++nt) {
        float bv = b3[wv * 64 + nt * 16 + cl];
        #pragma unroll
        for (int j = 0; j < 4; ++j) acc[nt][j] += bv;
    }

    #pragma unroll
    for (int j = 0; j < 4; ++j) {
        float s = acc[0][j] + acc[1][j] + acc[2][j] + acc[3][j];
        float q = acc[0][j]*acc[0][j] + acc[1][j]*acc[1][j] + acc[2][j]*acc[2][j] + acc[3][j]*acc[3][j];
        #pragma unroll
        for (int m = 1; m < 16; m <<= 1) { s += __shfl_xor(s, m); q += __shfl_xor(q, m); }
        if (cl == 0) { sS[wv][quad * 4 + j] = s; sQ[wv][quad * 4 + j] = q; }
    }
    __syncthreads();
    float meanr[4], rstdr[4];
    #pragma unroll
    for (int j = 0; j < 4; ++j) {
        const int row = quad * 4 + j;
        float s = sS[0][row] + sS[1][row] + sS[2][row] + sS[3][row];
        float q = sQ[0][row] + sQ[1][row] + sQ[2][row] + sQ[3][row];
        float mean = s * (1.f / 256.f);
        float var  = q * (1.f / 256.f) - mean * mean;
        meanr[j] = mean;
        rstdr[j] = rsqrtf(fmaxf(var, 0.f) + LN_EPS);
    }

    #pragma unroll
    for (int j = 0; j < 4; ++j) {
        float p = 0.f;
        #pragma unroll
        for (int nt = 0; nt < 4; ++nt) {
            const int col = wv * 64 + nt * 16 + cl;
            float h = fmaxf((acc[nt][j] - meanr[j]) * rstdr[j] * g3[col] + bb3[col], 0.f);
            p += h * w4[col];
        }
        #pragma unroll
        for (int m = 1; m < 16; m <<= 1) p += __shfl_xor(p, m);
        if (cl == 0) sP[wv][quad * 4 + j] = p;
    }
    __syncthreads();
    if (t < 16) {
        float p = sP[0][t] + sP[1][t] + sP[2][t] + sP[3][t];
        out[m0 + t] = 1.f / (1.f + expf(-(p + b4[0])));
    }
}

// ---------------------------------------------------------------------------
extern "C" void kernel_launch(void* const* d_in, const int* in_sizes, int n_in,
                              void* d_out, int out_size, void* d_ws, size_t ws_size,
                              hipStream_t stream)
{
    (void)in_sizes; (void)n_in; (void)out_size; (void)ws_size;
    const int*   target_ad       = (const int*)d_in[0];
    const int*   ubs_feature     = (const int*)d_in[1];
    const int*   profile_feature = (const int*)d_in[2];
    const float* context         = (const float*)d_in[3];
    const float* item_tables     = (const float*)d_in[4];
    const float* profile_tables  = (const float*)d_in[5];
    const float* q_w   = (const float*)d_in[6];
    const float* k_w   = (const float*)d_in[7];
    const float* v_w   = (const float*)d_in[8];
    const float* lin_w = (const float*)d_in[9];
    const float* lin_b = (const float*)d_in[10];
    const float* ln_g  = (const float*)d_in[11];
    const float* ln_b  = (const float*)d_in[12];
    const float* t_w1  = (const float*)d_in[13];
    const float* t_b1  = (const float*)d_in[14];
    const float* t_g1  = (const float*)d_in[15];
    const float* t_bb1 = (const float*)d_in[16];
    const float* t_w2  = (const float*)d_in[17];
    const float* t_b2  = (const float*)d_in[18];
    const float* t_g2  = (const float*)d_in[19];
    const float* t_bb2 = (const float*)d_in[20];
    const float* t_w3  = (const float*)d_in[21];
    const float* t_b3  = (const float*)d_in[22];
    const float* t_g3  = (const float*)d_in[23];
    const float* t_bb3 = (const float*)d_in[24];
    const float* t_w4  = (const float*)d_in[25];
    const float* t_b4  = (const float*)d_in[26];

    char* ws = (char*)d_ws;
    unsigned short* wsMT = (unsigned short*)(ws);              //  3,276,800
    unsigned short* wsWT = (unsigned short*)(ws +  3276800);   //  3,276,800
    float* ubs_acc       = (float*)         (ws +  6553600);   //    524,288
    unsigned short* Wt1  = (unsigned short*)(ws +  7077888);   //  2,686,976
    unsigned short* Wt2  = (unsigned short*)(ws +  9764864);   //  1,048,576
    unsigned short* Wt3  = (unsigned short*)(ws + 10813440);   //    262,144
    float*          C1   = (float*)         (ws + 11075584);   //  1,048,576
    float*          C2   = (float*)         (ws + 12124160);   //    524,288 (end 12,648,448)

    pre_kernel<<<528, 256, 0, stream>>>(q_w, k_w, v_w, lin_w, wsMT, wsWT, ubs_acc);
    attn_kernel<<<ATTN_BLKS_ + 1952, 256, 0, stream>>>(ubs_feature, item_tables, wsMT, wsWT,
                                                       lin_b, ln_g, ln_b, ubs_acc,
                                                       t_w1, t_w2, t_w3, Wt1, Wt2, Wt3);
    gemm1x_kernel<<<256, 256, 0, stream>>>(ubs_acc, target_ad, profile_feature, context,
                                           item_tables, profile_tables, Wt1, t_b1, C1);
    gemm2f_kernel<<<128, 256, 0, stream>>>(C1, t_g1, t_bb1, Wt2, t_b2, C2);
    gemm3f_kernel<<<16, 256, 0, stream>>>(C2, t_g2, t_bb2, Wt3, t_b3,
                                          t_g3, t_bb3, t_w4, t_b4, (float*)d_out);
}

// Round 13
// 233.797 us; speedup vs baseline: 1.2426x; 1.0363x over previous
//
#include <hip/hip_runtime.h>
#include <hip/hip_bf16.h>

#define B_ 256
#define L_ 100
#define F_ 8
#define P_ 4
#define E_ 64
#define H_ 4
#define D_ 64
#define C_ 32
#define V_ 10000
#define TOWER_IN_ 1312
#define LN_EPS 0.001f
#define LCHMAX_ 5  // max l's per attention block (chunks 0-3: 5 l's, 4-23: 4 l's)
#define NCH_ 24    // number of l-chunks (4*5 + 20*4 = 100 l's)
#define ZK_ 40     // padded k-stride for sZt (80B: 16B-aligned, conflict-free)
#define ATTN_BLKS_ (NCH_ * 32)   // 768 = exactly 3 blocks/CU on 256 CUs

typedef __attribute__((ext_vector_type(8))) short bf8v;           // 8 bf16 (4 VGPRs)
typedef __attribute__((ext_vector_type(8))) unsigned short us8;   // 8 u16
typedef __attribute__((ext_vector_type(4))) float f4v;            // 4 f32 acc

__device__ __forceinline__ unsigned short f2bf(float x) {
    __hip_bfloat16 h = __float2bfloat16(x);
    return __builtin_bit_cast(unsigned short, h);
}

// raw barrier: LDS-drain + s_barrier, NO vmcnt drain (prefetch loads stay in flight)
#define BARRIER() do { \
    asm volatile("s_waitcnt lgkmcnt(0)" ::: "memory"); \
    __builtin_amdgcn_s_barrier(); \
    asm volatile("" ::: "memory"); \
} while (0)

// ---------------------------------------------------------------------------
// Kernel PRE: precomp (register-tiled f32) + ubs_acc zero.
// ---------------------------------------------------------------------------
__global__ __launch_bounds__(256) void pre_kernel(
    const float* __restrict__ q_w, const float* __restrict__ k_w,
    const float* __restrict__ v_w, const float* __restrict__ lin_w,
    unsigned short* __restrict__ wsMT, unsigned short* __restrict__ wsWT,
    float* __restrict__ ubs_acc)
{
    __shared__ float sA[64][68];
    __shared__ float sB[64][68];
    const int t = threadIdx.x;
    const int bx = blockIdx.x;

    if (bx >= 400) {
        const int bi = bx - 400;                   // 128 blocks x 1024 floats
        float4 z = {0.f, 0.f, 0.f, 0.f};
        *(float4*)(ubs_acc + (size_t)bi * 1024 + t * 4) = z;
        return;
    }

    const int l = bx >> 2;
    const int h = bx & 3;
    const size_t obase = (size_t)(l * 4 + h) * 4096;
    const int te = t & 15, to = t >> 4;

    for (int i = 0; i < 16; ++i) {
        int idx = t + i * 256;
        int e = idx >> 6, d = idx & 63;
        sA[e][d] = q_w[(l * 64 + e) * 256 + h * 64 + d];
        sB[e][d] = k_w[(l * 64 + e) * 256 + h * 64 + d];
    }
    __syncthreads();
    {
        float acc[4][4];
        #pragma unroll
        for (int i = 0; i < 4; ++i)
            #pragma unroll
            for (int j = 0; j < 4; ++j) acc[i][j] = 0.f;
        for (int d0 = 0; d0 < 64; d0 += 4) {
            float4 a4[4], b4[4];
            #pragma unroll
            for (int i = 0; i < 4; ++i) a4[i] = *(const float4*)&sA[te + 16 * i][d0];
            #pragma unroll
            for (int j = 0; j < 4; ++j) b4[j] = *(const float4*)&sB[to + 16 * j][d0];
            #pragma unroll
            for (int i = 0; i < 4; ++i)
                #pragma unroll
                for (int j = 0; j < 4; ++j) {
                    acc[i][j] += a4[i].x * b4[j].x;
                    acc[i][j] += a4[i].y * b4[j].y;
                    acc[i][j] += a4[i].z * b4[j].z;
                    acc[i][j] += a4[i].w * b4[j].w;
                }
        }
        #pragma unroll
        for (int j = 0; j < 4; ++j)
            #pragma unroll
            for (int i = 0; i < 4; ++i)
                wsMT[obase + (to + 16 * j) * 64 + (te + 16 * i)] = f2bf(acc[i][j]);
    }
    __syncthreads();

    for (int i = 0; i < 16; ++i) {
        int idx = t + i * 256;
        int e = idx >> 6, d = idx & 63;
        sA[e][d] = v_w[(l * 64 + e) * 256 + h * 64 + d];
        int oo = idx & 63, dd = idx >> 6;
        sB[oo][dd] = lin_w[l * 16384 + (h * 64 + dd) * 64 + oo];
    }
    __syncthreads();
    {
        float acc[4][4];
        #pragma unroll
        for (int i = 0; i < 4; ++i)
            #pragma unroll
            for (int j = 0; j < 4; ++j) acc[i][j] = 0.f;
        for (int d0 = 0; d0 < 64; d0 += 4) {
            float4 a4[4], b4[4];
            #pragma unroll
            for (int i = 0; i < 4; ++i) a4[i] = *(const float4*)&sA[te + 16 * i][d0];
            #pragma unroll
            for (int j = 0; j < 4; ++j) b4[j] = *(const float4*)&sB[to + 16 * j][d0];
            #pragma unroll
            for (int i = 0; i < 4; ++i)
                #pragma unroll
                for (int j = 0; j < 4; ++j) {
                    acc[i][j] += a4[i].x * b4[j].x;
                    acc[i][j] += a4[i].y * b4[j].y;
                    acc[i][j] += a4[i].z * b4[j].z;
                    acc[i][j] += a4[i].w * b4[j].w;
                }
        }
        #pragma unroll
        for (int j = 0; j < 4; ++j)
            #pragma unroll
            for (int i = 0; i < 4; ++i)
                wsWT[obase + (to + 16 * j) * 64 + (te + 16 * i)] = f2bf(acc[i][j]);
    }
}

// ---------------------------------------------------------------------------
// Kernel A: fused attention (blocks < 768) + tower weight prep (blocks >= 768).
// 768 attn blocks = exactly 3/CU, 1 residency round, uniform load (R11/R12).
// This round: s_setprio(1) around MFMA clusters (T5: helps when co-resident
// blocks are at different phases — our regime).
// ---------------------------------------------------------------------------
__global__ __launch_bounds__(256, 3) void attn_kernel(
    const int* __restrict__ ubs_feature, const float* __restrict__ item_tables,
    const unsigned short* __restrict__ wsMT, const unsigned short* __restrict__ wsWT,
    const float* __restrict__ lin_b, const float* __restrict__ ln_g,
    const float* __restrict__ ln_b, float* __restrict__ ubs_acc,
    const float* __restrict__ w1, const float* __restrict__ w2,
    const float* __restrict__ w3,
    unsigned short* __restrict__ Wt1, unsigned short* __restrict__ Wt2,
    unsigned short* __restrict__ Wt3)
{
    __shared__ __align__(16) unsigned short sUE[64][72];       // rows=b_loc*8+f
    __shared__ __align__(16) unsigned short sT[64][136];       // cols=hl*64+e'
    __shared__ __align__(16) unsigned short sZt[4][64][ZK_];   // [pair][e][k] (k<32 used)
    __shared__ __align__(16) unsigned short sAblk[4][16][32];  // [pair][r][k]
    __shared__ float sLng[64], sLnb[64], sLinb[LCHMAX_][64];

    const int t = threadIdx.x;

    if (blockIdx.x >= ATTN_BLKS_) {
        // ---------------- prep (weight transpose) ----------------
        float (*tile)[33] = (float (*)[33])sT;   // 32x33 f32 fits in sT region
        int bi = blockIdx.x - ATTN_BLKS_;
        const float* src; unsigned short* dst; int K, N, tk, tn;
        if (bi < 1312)      { src = w1; dst = Wt1; K = 1312; N = 1024; tk = bi / 32;  tn = bi % 32; }
        else if (bi < 1824) { int i = bi - 1312; src = w2; dst = Wt2; K = 1024; N = 512; tk = i / 16; tn = i % 16; }
        else                { int i = bi - 1824; src = w3; dst = Wt3; K = 512;  N = 256; tk = i / 8;  tn = i % 8; }
        const int k0 = tk * 32, n0 = tn * 32;
        const int rr = t >> 5, cc = t & 31;
        #pragma unroll
        for (int i = 0; i < 4; ++i) {
            int r = rr * 4 + i;
            tile[r][cc] = src[(size_t)(k0 + r) * N + n0 + cc];
        }
        __syncthreads();
        #pragma unroll
        for (int i = 0; i < 4; ++i) {
            int r = rr * 4 + i;
            dst[(size_t)(n0 + r) * K + k0 + cc] = f2bf(tile[cc][r]);
        }
        return;
    }

    const int c = blockIdx.x >> 5;            // l-chunk 0..23
    const int lch   = (c < 4) ? 5 : 4;        // chunks 0-3: 5 l's; 4-23: 4 l's
    const int lbase = (c < 4) ? c * 5 : 20 + (c - 4) * 4;
    const int b0 = (blockIdx.x & 31) * 8;
    const int wv = t >> 6, lane = t & 63, quad = lane >> 4, cl = lane & 15;
    const int role = wv >> 1, hlw = wv & 1;

    const int grow = wv * 16 + (lane >> 2);   // row in [0,64) = b_loc*8 + f
    const int gseg = lane & 3;                // 16-float segment
    const int gb = b0 + (grow >> 3), gf = grow & 7;

    if (t < 64) { sLng[t] = ln_g[t]; sLnb[t] = ln_b[t]; }
    if (t >= 64 && t < 128) {
        for (int li = 0; li < lch; ++li)
            sLinb[li][t - 64] = lin_b[(lbase + li) * 64 + (t - 64)];
    }

    int vidx[LCHMAX_];
    for (int li = 0; li < lch; ++li)
        vidx[li] = ubs_feature[(gb * L_ + lbase + li) * F_ + gf];

    float4 pf[4];
    bf8v bfrag[4][2];

    auto load_bfrag = [&](int lh) {   // lh = l*4 + half*2 + hlw
        const unsigned short* Bsrc = (role == 0 ? wsMT : wsWT) + ((size_t)lh * 4096);
        #pragma unroll
        for (int nt = 0; nt < 4; ++nt)
            #pragma unroll
            for (int k2 = 0; k2 < 2; ++k2)
                bfrag[nt][k2] = *(const bf8v*)(Bsrc + (nt * 16 + cl) * 64 + k2 * 32 + quad * 8);
    };
    auto load_pf = [&](int li) {
        const float* srcp = item_tables + ((size_t)gf * V_ + vidx[li]) * 64 + gseg * 16;
        #pragma unroll
        for (int j = 0; j < 4; ++j) pf[j] = ((const float4*)srcp)[j];
    };
    auto store_ue = [&]() {
        us8 u0, u1;
        u0[0] = f2bf(pf[0].x); u0[1] = f2bf(pf[0].y); u0[2] = f2bf(pf[0].z); u0[3] = f2bf(pf[0].w);
        u0[4] = f2bf(pf[1].x); u0[5] = f2bf(pf[1].y); u0[6] = f2bf(pf[1].z); u0[7] = f2bf(pf[1].w);
        u1[0] = f2bf(pf[2].x); u1[1] = f2bf(pf[2].y); u1[2] = f2bf(pf[2].z); u1[3] = f2bf(pf[2].w);
        u1[4] = f2bf(pf[3].x); u1[5] = f2bf(pf[3].y); u1[6] = f2bf(pf[3].z); u1[7] = f2bf(pf[3].w);
        *(us8*)&sUE[grow][gseg * 16]     = u0;
        *(us8*)&sUE[grow][gseg * 16 + 8] = u1;
    };

    load_pf(0);
    load_bfrag(lbase * 4 + hlw);
    store_ue();
    BARRIER();

    float lnacc[16];
    #pragma unroll
    for (int i = 0; i < 16; ++i) lnacc[i] = 0.f;

    for (int li = 0; li < lch; ++li) {
        const int l = lbase + li;

        if (li + 1 < lch) load_pf(li + 1);

        f4v accO[4];
        #pragma unroll
        for (int nt = 0; nt < 4; ++nt) accO[nt] = {0.f, 0.f, 0.f, 0.f};

        #pragma unroll
        for (int half = 0; half < 2; ++half) {
            // ---- phase A: waves 0,1 -> T; waves 2,3 -> Zt ----
            __builtin_amdgcn_s_setprio(1);
            #pragma unroll
            for (int m = 0; m < 4; ++m) {
                bf8v a0 = *(const bf8v*)&sUE[m * 16 + cl][quad * 8];
                bf8v a1 = *(const bf8v*)&sUE[m * 16 + cl][32 + quad * 8];
                #pragma unroll
                for (int nt = 0; nt < 4; ++nt) {
                    f4v acc = {0.f, 0.f, 0.f, 0.f};
                    acc = __builtin_amdgcn_mfma_f32_16x16x32_bf16(a0, bfrag[nt][0], acc, 0, 0, 0);
                    acc = __builtin_amdgcn_mfma_f32_16x16x32_bf16(a1, bfrag[nt][1], acc, 0, 0, 0);
                    if (role == 0) {
                        #pragma unroll
                        for (int j = 0; j < 4; ++j)
                            sT[m * 16 + quad * 4 + j][hlw * 64 + nt * 16 + cl] = f2bf(acc[j]);
                    } else {
                        ushort4 zp;
                        zp.x = f2bf(acc[0]); zp.y = f2bf(acc[1]);
                        zp.z = f2bf(acc[2]); zp.w = f2bf(acc[3]);
                        const int k0 = (quad >> 1) * 16 + hlw * 8 + (quad & 1) * 4;
                        *(ushort4*)&sZt[m][nt * 16 + cl][k0] = zp;
                    }
                }
            }
            __builtin_amdgcn_s_setprio(0);
            if (half == 0)          load_bfrag(l * 4 + 2 + hlw);
            else if (li + 1 < lch)  load_bfrag((l + 1) * 4 + hlw);
            BARRIER();

            // ---- scores + softmax + Ablk (wave = pair) ----
            {
                const int p = wv;
                const bool valid = (cl >> 3) == (quad >> 1);
                bf8v u0 = *(const bf8v*)&sUE[p * 16 + cl][quad * 8];
                bf8v u1 = *(const bf8v*)&sUE[p * 16 + cl][32 + quad * 8];
                #pragma unroll
                for (int hl = 0; hl < 2; ++hl) {
                    bf8v a0s = *(const bf8v*)&sT[p * 16 + cl][hl * 64 + quad * 8];
                    bf8v a1s = *(const bf8v*)&sT[p * 16 + cl][hl * 64 + 32 + quad * 8];
                    f4v acc = {0.f, 0.f, 0.f, 0.f};
                    acc = __builtin_amdgcn_mfma_f32_16x16x32_bf16(a0s, u0, acc, 0, 0, 0);
                    acc = __builtin_amdgcn_mfma_f32_16x16x32_bf16(a1s, u1, acc, 0, 0, 0);
                    const int kk = hl * 8 + (cl & 7) + (cl >> 3) * 16;
                    #pragma unroll
                    for (int j = 0; j < 4; ++j) {
                        float v = acc[j] * 0.125f;
                        float mx = v;
                        mx = fmaxf(mx, __shfl_xor(mx, 1));
                        mx = fmaxf(mx, __shfl_xor(mx, 2));
                        mx = fmaxf(mx, __shfl_xor(mx, 4));
                        float ex = __expf(v - mx);
                        float sm = ex;
                        sm += __shfl_xor(sm, 1);
                        sm += __shfl_xor(sm, 2);
                        sm += __shfl_xor(sm, 4);
                        float aw = valid ? ex * __builtin_amdgcn_rcpf(sm) : 0.f;
                        sAblk[p][quad * 4 + j][kk] = f2bf(aw);
                    }
                }
            }

            // ---- PV (same-wave sAblk dependency: no barrier needed) ----
            {
                const int p = wv;
                bf8v a0p = *(const bf8v*)&sAblk[p][cl][quad * 8];
                __builtin_amdgcn_s_setprio(1);
                #pragma unroll
                for (int nt = 0; nt < 4; ++nt) {
                    bf8v bz = *(const bf8v*)&sZt[p][nt * 16 + cl][quad * 8];
                    accO[nt] = __builtin_amdgcn_mfma_f32_16x16x32_bf16(a0p, bz, accO[nt], 0, 0, 0);
                }
                __builtin_amdgcn_s_setprio(0);
            }
            // write next-l UE rows before the half-1 barrier.  4 barriers/l.
            if (half == 1 && li + 1 < lch) store_ue();
            BARRIER();
        }

        // ---- +lin_b, LayerNorm per row over 64 cols, accumulate over l ----
        {
            float x[16];
            #pragma unroll
            for (int nt = 0; nt < 4; ++nt)
                #pragma unroll
                for (int j = 0; j < 4; ++j)
                    x[nt * 4 + j] = accO[nt][j] + sLinb[li][nt * 16 + cl];
            #pragma unroll
            for (int j = 0; j < 4; ++j) {
                float s = x[j] + x[4 + j] + x[8 + j] + x[12 + j];
                #pragma unroll
                for (int m = 1; m < 16; m <<= 1) s += __shfl_xor(s, m);
                float mean = s * (1.f / 64.f);
                float q = 0.f;
                #pragma unroll
                for (int nt = 0; nt < 4; ++nt) { float d = x[nt * 4 + j] - mean; q += d * d; }
                #pragma unroll
                for (int m = 1; m < 16; m <<= 1) q += __shfl_xor(q, m);
                float rst = rsqrtf(q * (1.f / 64.f) + LN_EPS);
                #pragma unroll
                for (int nt = 0; nt < 4; ++nt) {
                    int col = nt * 16 + cl;
                    lnacc[nt * 4 + j] += (x[nt * 4 + j] - mean) * rst * sLng[col] + sLnb[col];
                }
            }
        }
    }

    #pragma unroll
    for (int j = 0; j < 4; ++j) {
        const int row = wv * 16 + quad * 4 + j;
        const int b = b0 + (row >> 3), f = row & 7;
        #pragma unroll
        for (int nt = 0; nt < 4; ++nt)
            atomicAdd(&ubs_acc[(size_t)b * 512 + f * 64 + nt * 16 + cl], lnacc[nt * 4 + j]);
    }
}

// ---------------------------------------------------------------------------
// partial gemm over K-range: acc += LDS-A-row . B-row,  dual chains.
// ---------------------------------------------------------------------------
__device__ __forceinline__ f4v gemm_krange(
    const unsigned short* sArow, const unsigned short* __restrict__ brow,
    int klo, int khi)
{
    f4v acc0 = {0.f, 0.f, 0.f, 0.f};
    f4v acc1 = {0.f, 0.f, 0.f, 0.f};
    int k0 = klo;
    for (; k0 + 64 <= khi; k0 += 64) {
        bf8v a0 = *(const bf8v*)(sArow + k0);
        bf8v b0 = *(const bf8v*)(brow + k0);
        bf8v a1 = *(const bf8v*)(sArow + k0 + 32);
        bf8v b1 = *(const bf8v*)(brow + k0 + 32);
        acc0 = __builtin_amdgcn_mfma_f32_16x16x32_bf16(a0, b0, acc0, 0, 0, 0);
        acc1 = __builtin_amdgcn_mfma_f32_16x16x32_bf16(a1, b1, acc1, 0, 0, 0);
    }
    if (k0 < khi) {
        bf8v a = *(const bf8v*)(sArow + k0);
        bf8v b = *(const bf8v*)(brow + k0);
        acc0 = __builtin_amdgcn_mfma_f32_16x16x32_bf16(a, b, acc0, 0, 0, 0);
    }
    #pragma unroll
    for (int j = 0; j < 4; ++j) acc0[j] += acc1[j];
    return acc0;
}

// ---------------------------------------------------------------------------
// LN-from-C into LDS bf16, 512-thread version (16 rows; row = t>>5, sub = t&31)
// ---------------------------------------------------------------------------
__device__ __forceinline__ void ln_rows_to_lds512(
    const float* __restrict__ Cd, int N, int m0,
    const float* __restrict__ g, const float* __restrict__ bb,
    unsigned short* sH, int lda, int t, float invN)
{
    const int r = t >> 5, sub = t & 31;
    const float* crow = Cd + (size_t)(m0 + r) * N;
    float s = 0.f, s2 = 0.f;
    for (int j = sub * 4; j < N; j += 128) {
        float4 x = *(const float4*)(crow + j);
        s  += x.x + x.y + x.z + x.w;
        s2 += x.x * x.x + x.y * x.y + x.z * x.z + x.w * x.w;
    }
    #pragma unroll
    for (int m = 1; m < 32; m <<= 1) { s += __shfl_xor(s, m); s2 += __shfl_xor(s2, m); }
    const float mean = s * invN;
    const float var  = s2 * invN - mean * mean;
    const float rst  = rsqrtf(fmaxf(var, 0.f) + LN_EPS);
    for (int j = sub * 4; j < N; j += 128) {
        float4 x = *(const float4*)(crow + j);
        ushort4 o;
        o.x = f2bf(fmaxf((x.x - mean) * rst * g[j]     + bb[j],     0.f));
        o.y = f2bf(fmaxf((x.y - mean) * rst * g[j + 1] + bb[j + 1], 0.f));
        o.z = f2bf(fmaxf((x.z - mean) * rst * g[j + 2] + bb[j + 2], 0.f));
        o.w = f2bf(fmaxf((x.w - mean) * rst * g[j + 3] + bb[j + 3], 0.f));
        *(ushort4*)&sH[r * lda + j] = o;
    }
}

// ---------------------------------------------------------------------------
// Kernel G1: X-build (LDS) + gemm1 split-K -> C1 f32.
// grid (16 n x 16 m) = 256 blocks x 512 threads (8 waves = 4 n-sub x 2 k-half):
// 2 waves/SIMD for latency hiding (was 1 wave/SIMD at 256 threads).
// ---------------------------------------------------------------------------
#define XLD 1320
__global__ __launch_bounds__(512) void gemm1x_kernel(
    const float* __restrict__ ubs_acc,
    const int* __restrict__ target_ad, const int* __restrict__ profile_feature,
    const float* __restrict__ context,
    const float* __restrict__ item_tables, const float* __restrict__ profile_tables,
    const unsigned short* __restrict__ Wt1, const float* __restrict__ b1,
    float* __restrict__ C1)
{
    __shared__ __align__(16) unsigned short sX[16][XLD];   // 42,240 B
    __shared__ float sRed[4][16][16];                      //  4,096 B
    const int t = threadIdx.x;
    const int wv = t >> 6, lane = t & 63, quad = lane >> 4, cl = lane & 15;
    const int nw = wv & 3, kh = wv >> 2;
    const int m0 = (blockIdx.x >> 4) * 16;
    const int n0w = (blockIdx.x & 15) * 64 + nw * 16;

    // build X rows m0..m0+15 (512 threads: row = t>>5, 32 threads/row)
    {
        const int r = t >> 5, sub = t & 31;
        const int gb = m0 + r;
        #pragma unroll
        for (int k = 0; k < 11; ++k) {
            int cc = sub * 4 + k * 128;
            if (cc >= TOWER_IN_) break;
            float4 x;
            if (cc < 512) {
                x = *(const float4*)(ubs_acc + (size_t)gb * 512 + cc);
                x.x = fmaxf(x.x * 0.01f, 0.f); x.y = fmaxf(x.y * 0.01f, 0.f);
                x.z = fmaxf(x.z * 0.01f, 0.f); x.w = fmaxf(x.w * 0.01f, 0.f);
            } else if (cc < 1024) {
                int f = (cc - 512) >> 6, e = (cc - 512) & 63;
                x = *(const float4*)(item_tables + ((size_t)f * V_ + target_ad[gb * 8 + f]) * 64 + e);
            } else if (cc < 1280) {
                int pp = (cc - 1024) >> 6, e = (cc - 1024) & 63;
                x = *(const float4*)(profile_tables + ((size_t)pp * V_ + profile_feature[gb * 4 + pp]) * 64 + e);
            } else {
                x = *(const float4*)(context + (size_t)gb * 32 + (cc - 1280));
            }
            ushort4 o;
            o.x = f2bf(x.x); o.y = f2bf(x.y); o.z = f2bf(x.z); o.w = f2bf(x.w);
            *(ushort4*)&sX[r][cc] = o;
        }
    }
    __syncthreads();

    const unsigned short* arow = &sX[0][0] + cl * XLD + quad * 8;
    const unsigned short* brow = Wt1 + (size_t)(n0w + cl) * 1312 + quad * 8;
    f4v part = gemm_krange(arow, brow, kh ? 672 : 0, kh ? 1312 : 672);  // 672 = 21*32

    if (kh == 1) {
        #pragma unroll
        for (int j = 0; j < 4; ++j) sRed[nw][quad * 4 + j][cl] = part[j];
    }
    __syncthreads();
    if (kh == 0) {
        float bv = b1[n0w + cl];
        #pragma unroll
        for (int j = 0; j < 4; ++j)
            C1[(size_t)(m0 + quad * 4 + j) * 1024 + n0w + cl] =
                part[j] + sRed[nw][quad * 4 + j][cl] + bv;
    }
}

// ---------------------------------------------------------------------------
// Kernel G2: LN1(C1)+ReLU (LDS) + gemm2 split-K -> C2 f32.
// grid (8 n x 16 m) = 128 blocks x 512 threads.
// ---------------------------------------------------------------------------
#define H1LD 1032
__global__ __launch_bounds__(512) void gemm2f_kernel(
    const float* __restrict__ C1, const float* __restrict__ g1,
    const float* __restrict__ bb1,
    const unsigned short* __restrict__ Wt2, const float* __restrict__ b2,
    float* __restrict__ C2)
{
    __shared__ __align__(16) unsigned short sH[16][H1LD];  // 33,024 B
    __shared__ float sRed[4][16][16];                      //  4,096 B
    const int t = threadIdx.x;
    const int wv = t >> 6, lane = t & 63, quad = lane >> 4, cl = lane & 15;
    const int nw = wv & 3, kh = wv >> 2;
    const int m0 = (blockIdx.x >> 3) * 16;
    const int n0w = (blockIdx.x & 7) * 64 + nw * 16;

    ln_rows_to_lds512(C1, 1024, m0, g1, bb1, &sH[0][0], H1LD, t, 1.f / 1024.f);
    __syncthreads();

    const unsigned short* arow = &sH[0][0] + cl * H1LD + quad * 8;
    const unsigned short* brow = Wt2 + (size_t)(n0w + cl) * 1024 + quad * 8;
    f4v part = gemm_krange(arow, brow, kh ? 512 : 0, kh ? 1024 : 512);

    if (kh == 1) {
        #pragma unroll
        for (int j = 0; j < 4; ++j) sRed[nw][quad * 4 + j][cl] = part[j];
    }
    __syncthreads();
    if (kh == 0) {
        float bv = b2[n0w + cl];
        #pragma unroll
        for (int j = 0; j < 4; ++j)
            C2[(size_t)(m0 + quad * 4 + j) * 512 + n0w + cl] =
                part[j] + sRed[nw][quad * 4 + j][cl] + bv;
    }
}

// ---------------------------------------------------------------------------
// LN-from-C into LDS bf16 (256-thread version, for gemm3f).
// ---------------------------------------------------------------------------
__device__ __forceinline__ void ln_rows_to_lds(
    const float* __restrict__ Cd, int N, int m0,
    const float* __restrict__ g, const float* __restrict__ bb,
    unsigned short* sH, int lda, int t, float invN)
{
    const int r = t >> 4, sub = t & 15;
    const float* crow = Cd + (size_t)(m0 + r) * N;
    float s = 0.f, s2 = 0.f;
    for (int j = sub * 4; j < N; j += 64) {
        float4 x = *(const float4*)(crow + j);
        s  += x.x + x.y + x.z + x.w;
        s2 += x.x * x.x + x.y * x.y + x.z * x.z + x.w * x.w;
    }
    #pragma unroll
    for (int m = 1; m < 16; m <<= 1) { s += __shfl_xor(s, m); s2 += __shfl_xor(s2, m); }
    const float mean = s * invN;
    const float var  = s2 * invN - mean * mean;
    const float rst  = rsqrtf(fmaxf(var, 0.f) + LN_EPS);
    for (int j = sub * 4; j < N; j += 64) {
        float4 x = *(const float4*)(crow + j);
        ushort4 o;
        o.x = f2bf(fmaxf((x.x - mean) * rst * g[j]     + bb[j],     0.f));
        o.y = f2bf(fmaxf((x.y - mean) * rst * g[j + 1] + bb[j + 1], 0.f));
        o.z = f2bf(fmaxf((x.z - mean) * rst * g[j + 2] + bb[j + 2], 0.f));
        o.w = f2bf(fmaxf((x.w - mean) * rst * g[j + 3] + bb[j + 3], 0.f));
        *(ushort4*)&sH[r * lda + j] = o;
    }
}

// ---------------------------------------------------------------------------
// Kernel G3: LN2(C2)+ReLU (LDS) + gemm3 (full 256-col rows) + LN3 + ReLU +
// dot(w4) + sigmoid -> out.  grid = 16 blocks (16 rows each), 256 threads.
// ---------------------------------------------------------------------------
#define H2LD 520
__global__ __launch_bounds__(256) void gemm3f_kernel(
    const float* __restrict__ C2, const float* __restrict__ g2,
    const float* __restrict__ bb2,
    const unsigned short* __restrict__ Wt3, const float* __restrict__ b3,
    const float* __restrict__ g3, const float* __restrict__ bb3,
    const float* __restrict__ w4, const float* __restrict__ b4,
    float* __restrict__ out)
{
    __shared__ __align__(16) unsigned short sH[16][H2LD];
    __shared__ float sS[4][16], sQ[4][16], sP[4][16];
    const int t = threadIdx.x;
    const int wv = t >> 6, lane = t & 63, quad = lane >> 4, cl = lane & 15;
    const int m0 = blockIdx.x * 16;

    ln_rows_to_lds(C2, 512, m0, g2, bb2, &sH[0][0], H2LD, t, 1.f / 512.f);
    __syncthreads();

    f4v acc[4];
    #pragma unroll
    for (int nt = 0; nt < 4; ++nt) acc[nt] = {0.f, 0.f, 0.f, 0.f};
    for (int k0 = 0; k0 < 512; k0 += 32) {
        bf8v a = *(const bf8v*)&sH[cl][k0 + quad * 8];
        #pragma unroll
        for (int nt = 0; nt < 4; ++nt) {
            const int col0 = wv * 64 + nt * 16;
            bf8v b = *(const bf8v*)(Wt3 + (size_t)(col0 + cl) * 512 + k0 + quad * 8);
            acc[nt] = __builtin_amdgcn_mfma_f32_16x16x32_bf16(a, b, acc[nt], 0, 0, 0);
        }
    }
    #pragma unroll
    for (int nt = 0; nt < 4; ++nt) {
        float bv = b3[wv * 64 + nt * 16 + cl];
        #pragma unroll
        for (int j = 0; j < 4; ++j) acc[nt][j] += bv;
    }

    #pragma unroll
    for (int j = 0; j < 4; ++j) {
        float s = acc[0][j] + acc[1][j] + acc[2][j] + acc[3][j];
        float q = acc[0][j]*acc[0][j] + acc[1][j]*acc[1][j] + acc[2][j]*acc[2][j] + acc[3][j]*acc[3][j];
        #pragma unroll
        for (int m = 1; m < 16; m <<= 1) { s += __shfl_xor(s, m); q += __shfl_xor(q, m); }
        if (cl == 0) { sS[wv][quad * 4 + j] = s; sQ[wv][quad * 4 + j] = q; }
    }
    __syncthreads();
    float meanr[4], rstdr[4];
    #pragma unroll
    for (int j = 0; j < 4; ++j) {
        const int row = quad * 4 + j;
        float s = sS[0][row] + sS[1][row] + sS[2][row] + sS[3][row];
        float q = sQ[0][row] + sQ[1][row] + sQ[2][row] + sQ[3][row];
        float mean = s * (1.f / 256.f);
        float var  = q * (1.f / 256.f) - mean * mean;
        meanr[j] = mean;
        rstdr[j] = rsqrtf(fmaxf(var, 0.f) + LN_EPS);
    }

    #pragma unroll
    for (int j = 0; j < 4; ++j) {
        float p = 0.f;
        #pragma unroll
        for (int nt = 0; nt < 4; ++nt) {
            const int col = wv * 64 + nt * 16 + cl;
            float h = fmaxf((acc[nt][j] - meanr[j]) * rstdr[j] * g3[col] + bb3[col], 0.f);
            p += h * w4[col];
        }
        #pragma unroll
        for (int m = 1; m < 16; m <<= 1) p += __shfl_xor(p, m);
        if (cl == 0) sP[wv][quad * 4 + j] = p;
    }
    __syncthreads();
    if (t < 16) {
        float p = sP[0][t] + sP[1][t] + sP[2][t] + sP[3][t];
        out[m0 + t] = 1.f / (1.f + expf(-(p + b4[0])));
    }
}

// ---------------------------------------------------------------------------
extern "C" void kernel_launch(void* const* d_in, const int* in_sizes, int n_in,
                              void* d_out, int out_size, void* d_ws, size_t ws_size,
                              hipStream_t stream)
{
    (void)in_sizes; (void)n_in; (void)out_size; (void)ws_size;
    const int*   target_ad       = (const int*)d_in[0];
    const int*   ubs_feature     = (const int*)d_in[1];
    const int*   profile_feature = (const int*)d_in[2];
    const float* context         = (const float*)d_in[3];
    const float* item_tables     = (const float*)d_in[4];
    const float* profile_tables  = (const float*)d_in[5];
    const float* q_w   = (const float*)d_in[6];
    const float* k_w   = (const float*)d_in[7];
    const float* v_w   = (const float*)d_in[8];
    const float* lin_w = (const float*)d_in[9];
    const float* lin_b = (const float*)d_in[10];
    const float* ln_g  = (const float*)d_in[11];
    const float* ln_b  = (const float*)d_in[12];
    const float* t_w1  = (const float*)d_in[13];
    const float* t_b1  = (const float*)d_in[14];
    const float* t_g1  = (const float*)d_in[15];
    const float* t_bb1 = (const float*)d_in[16];
    const float* t_w2  = (const float*)d_in[17];
    const float* t_b2  = (const float*)d_in[18];
    const float* t_g2  = (const float*)d_in[19];
    const float* t_bb2 = (const float*)d_in[20];
    const float* t_w3  = (const float*)d_in[21];
    const float* t_b3  = (const float*)d_in[22];
    const float* t_g3  = (const float*)d_in[23];
    const float* t_bb3 = (const float*)d_in[24];
    const float* t_w4  = (const float*)d_in[25];
    const float* t_b4  = (const float*)d_in[26];

    char* ws = (char*)d_ws;
    unsigned short* wsMT = (unsigned short*)(ws);              //  3,276,800
    unsigned short* wsWT = (unsigned short*)(ws +  3276800);   //  3,276,800
    float* ubs_acc       = (float*)         (ws +  6553600);   //    524,288
    unsigned short* Wt1  = (unsigned short*)(ws +  7077888);   //  2,686,976
    unsigned short* Wt2  = (unsigned short*)(ws +  9764864);   //  1,048,576
    unsigned short* Wt3  = (unsigned short*)(ws + 10813440);   //    262,144
    float*          C1   = (float*)         (ws + 11075584);   //  1,048,576
    float*          C2   = (float*)         (ws + 12124160);   //    524,288 (end 12,648,448)

    pre_kernel<<<528, 256, 0, stream>>>(q_w, k_w, v_w, lin_w, wsMT, wsWT, ubs_acc);
    attn_kernel<<<ATTN_BLKS_ + 1952, 256, 0, stream>>>(ubs_feature, item_tables, wsMT, wsWT,
                                                       lin_b, ln_g, ln_b, ubs_acc,
                                                       t_w1, t_w2, t_w3, Wt1, Wt2, Wt3);
    gemm1x_kernel<<<256, 512, 0, stream>>>(ubs_acc, target_ad, profile_feature, context,
                                           item_tables, profile_tables, Wt1, t_b1, C1);
    gemm2f_kernel<<<128, 512, 0, stream>>>(C1, t_g1, t_bb1, Wt2, t_b2, C2);
    gemm3f_kernel<<<16, 256, 0, stream>>>(C2, t_g2, t_bb2, Wt3, t_b3,
                                          t_g3, t_bb3, t_w4, t_b4, (float*)d_out);
}

// Round 15
// 227.191 us; speedup vs baseline: 1.2787x; 1.0291x over previous
//
#include <hip/hip_runtime.h>
#include <hip/hip_bf16.h>

#define B_ 256
#define L_ 100
#define F_ 8
#define P_ 4
#define E_ 64
#define H_ 4
#define D_ 64
#define C_ 32
#define V_ 10000
#define TOWER_IN_ 1312
#define LN_EPS 0.001f
#define LCHMAX_ 5  // max l's per attention block (chunks 0-3: 5 l's, 4-23: 4 l's)
#define NCH_ 24    // number of l-chunks (4*5 + 20*4 = 100 l's)
#define ZK_ 40     // padded k-stride for sZt (80B: 16B-aligned, conflict-free)
#define ATTN_BLKS_ (NCH_ * 32)   // 768 = exactly 3 blocks/CU on 256 CUs

typedef __attribute__((ext_vector_type(8))) short bf8v;           // 8 bf16 (4 VGPRs)
typedef __attribute__((ext_vector_type(8))) unsigned short us8;   // 8 u16
typedef __attribute__((ext_vector_type(4))) float f4v;            // 4 f32 acc

__device__ __forceinline__ unsigned short f2bf(float x) {
    __hip_bfloat16 h = __float2bfloat16(x);
    return __builtin_bit_cast(unsigned short, h);
}

// raw barrier: LDS-drain + s_barrier, NO vmcnt drain (prefetch loads stay in flight)
#define BARRIER() do { \
    asm volatile("s_waitcnt lgkmcnt(0)" ::: "memory"); \
    __builtin_amdgcn_s_barrier(); \
    asm volatile("" ::: "memory"); \
} while (0)

// ---------------------------------------------------------------------------
// Kernel PRE: precomp (register-tiled f32) + ubs_acc zero.
// ---------------------------------------------------------------------------
__global__ __launch_bounds__(256) void pre_kernel(
    const float* __restrict__ q_w, const float* __restrict__ k_w,
    const float* __restrict__ v_w, const float* __restrict__ lin_w,
    unsigned short* __restrict__ wsMT, unsigned short* __restrict__ wsWT,
    float* __restrict__ ubs_acc)
{
    __shared__ float sA[64][68];
    __shared__ float sB[64][68];
    const int t = threadIdx.x;
    const int bx = blockIdx.x;

    if (bx >= 400) {
        const int bi = bx - 400;                   // 128 blocks x 1024 floats
        float4 z = {0.f, 0.f, 0.f, 0.f};
        *(float4*)(ubs_acc + (size_t)bi * 1024 + t * 4) = z;
        return;
    }

    const int l = bx >> 2;
    const int h = bx & 3;
    const size_t obase = (size_t)(l * 4 + h) * 4096;
    const int te = t & 15, to = t >> 4;

    for (int i = 0; i < 16; ++i) {
        int idx = t + i * 256;
        int e = idx >> 6, d = idx & 63;
        sA[e][d] = q_w[(l * 64 + e) * 256 + h * 64 + d];
        sB[e][d] = k_w[(l * 64 + e) * 256 + h * 64 + d];
    }
    __syncthreads();
    {
        float acc[4][4];
        #pragma unroll
        for (int i = 0; i < 4; ++i)
            #pragma unroll
            for (int j = 0; j < 4; ++j) acc[i][j] = 0.f;
        for (int d0 = 0; d0 < 64; d0 += 4) {
            float4 a4[4], b4[4];
            #pragma unroll
            for (int i = 0; i < 4; ++i) a4[i] = *(const float4*)&sA[te + 16 * i][d0];
            #pragma unroll
            for (int j = 0; j < 4; ++j) b4[j] = *(const float4*)&sB[to + 16 * j][d0];
            #pragma unroll
            for (int i = 0; i < 4; ++i)
                #pragma unroll
                for (int j = 0; j < 4; ++j) {
                    acc[i][j] += a4[i].x * b4[j].x;
                    acc[i][j] += a4[i].y * b4[j].y;
                    acc[i][j] += a4[i].z * b4[j].z;
                    acc[i][j] += a4[i].w * b4[j].w;
                }
        }
        #pragma unroll
        for (int j = 0; j < 4; ++j)
            #pragma unroll
            for (int i = 0; i < 4; ++i)
                wsMT[obase + (to + 16 * j) * 64 + (te + 16 * i)] = f2bf(acc[i][j]);
    }
    __syncthreads();

    for (int i = 0; i < 16; ++i) {
        int idx = t + i * 256;
        int e = idx >> 6, d = idx & 63;
        sA[e][d] = v_w[(l * 64 + e) * 256 + h * 64 + d];
        int oo = idx & 63, dd = idx >> 6;
        sB[oo][dd] = lin_w[l * 16384 + (h * 64 + dd) * 64 + oo];
    }
    __syncthreads();
    {
        float acc[4][4];
        #pragma unroll
        for (int i = 0; i < 4; ++i)
            #pragma unroll
            for (int j = 0; j < 4; ++j) acc[i][j] = 0.f;
        for (int d0 = 0; d0 < 64; d0 += 4) {
            float4 a4[4], b4[4];
            #pragma unroll
            for (int i = 0; i < 4; ++i) a4[i] = *(const float4*)&sA[te + 16 * i][d0];
            #pragma unroll
            for (int j = 0; j < 4; ++j) b4[j] = *(const float4*)&sB[to + 16 * j][d0];
            #pragma unroll
            for (int i = 0; i < 4; ++i)
                #pragma unroll
                for (int j = 0; j < 4; ++j) {
                    acc[i][j] += a4[i].x * b4[j].x;
                    acc[i][j] += a4[i].y * b4[j].y;
                    acc[i][j] += a4[i].z * b4[j].z;
                    acc[i][j] += a4[i].w * b4[j].w;
                }
        }
        #pragma unroll
        for (int j = 0; j < 4; ++j)
            #pragma unroll
            for (int i = 0; i < 4; ++i)
                wsWT[obase + (to + 16 * j) * 64 + (te + 16 * i)] = f2bf(acc[i][j]);
    }
}

// ---------------------------------------------------------------------------
// Kernel A: fused attention (blocks < 768) + tower weight prep (blocks >= 768).
// 768 attn blocks = exactly 3/CU, 1 residency round, uniform load (R11/R12).
// LN hoisted before the half-1 barrier (register/stable-LDS only).
// ---------------------------------------------------------------------------
__global__ __launch_bounds__(256, 3) void attn_kernel(
    const int* __restrict__ ubs_feature, const float* __restrict__ item_tables,
    const unsigned short* __restrict__ wsMT, const unsigned short* __restrict__ wsWT,
    const float* __restrict__ lin_b, const float* __restrict__ ln_g,
    const float* __restrict__ ln_b, float* __restrict__ ubs_acc,
    const float* __restrict__ w1, const float* __restrict__ w2,
    const float* __restrict__ w3,
    unsigned short* __restrict__ Wt1, unsigned short* __restrict__ Wt2,
    unsigned short* __restrict__ Wt3)
{
    __shared__ __align__(16) unsigned short sUE[64][72];       // rows=b_loc*8+f
    __shared__ __align__(16) unsigned short sT[64][136];       // cols=hl*64+e'
    __shared__ __align__(16) unsigned short sZt[4][64][ZK_];   // [pair][e][k] (k<32 used)
    __shared__ __align__(16) unsigned short sAblk[4][16][32];  // [pair][r][k]
    __shared__ float sLng[64], sLnb[64], sLinb[LCHMAX_][64];

    const int t = threadIdx.x;

    if (blockIdx.x >= ATTN_BLKS_) {
        // ---------------- prep (weight transpose) ----------------
        float (*tile)[33] = (float (*)[33])sT;   // 32x33 f32 fits in sT region
        int bi = blockIdx.x - ATTN_BLKS_;
        const float* src; unsigned short* dst; int K, N, tk, tn;
        if (bi < 1312)      { src = w1; dst = Wt1; K = 1312; N = 1024; tk = bi / 32;  tn = bi % 32; }
        else if (bi < 1824) { int i = bi - 1312; src = w2; dst = Wt2; K = 1024; N = 512; tk = i / 16; tn = i % 16; }
        else                { int i = bi - 1824; src = w3; dst = Wt3; K = 512;  N = 256; tk = i / 8;  tn = i % 8; }
        const int k0 = tk * 32, n0 = tn * 32;
        const int rr = t >> 5, cc = t & 31;
        #pragma unroll
        for (int i = 0; i < 4; ++i) {
            int r = rr * 4 + i;
            tile[r][cc] = src[(size_t)(k0 + r) * N + n0 + cc];
        }
        __syncthreads();
        #pragma unroll
        for (int i = 0; i < 4; ++i) {
            int r = rr * 4 + i;
            dst[(size_t)(n0 + r) * K + k0 + cc] = f2bf(tile[cc][r]);
        }
        return;
    }

    const int c = blockIdx.x >> 5;            // l-chunk 0..23
    const int lch   = (c < 4) ? 5 : 4;        // chunks 0-3: 5 l's; 4-23: 4 l's
    const int lbase = (c < 4) ? c * 5 : 20 + (c - 4) * 4;
    const int b0 = (blockIdx.x & 31) * 8;
    const int wv = t >> 6, lane = t & 63, quad = lane >> 4, cl = lane & 15;
    const int role = wv >> 1, hlw = wv & 1;

    const int grow = wv * 16 + (lane >> 2);   // row in [0,64) = b_loc*8 + f
    const int gseg = lane & 3;                // 16-float segment
    const int gb = b0 + (grow >> 3), gf = grow & 7;

    if (t < 64) { sLng[t] = ln_g[t]; sLnb[t] = ln_b[t]; }
    if (t >= 64 && t < 128) {
        for (int li = 0; li < lch; ++li)
            sLinb[li][t - 64] = lin_b[(lbase + li) * 64 + (t - 64)];
    }

    int vidx[LCHMAX_];
    for (int li = 0; li < lch; ++li)
        vidx[li] = ubs_feature[(gb * L_ + lbase + li) * F_ + gf];

    float4 pf[4];
    bf8v bfrag[4][2];

    auto load_bfrag = [&](int lh) {   // lh = l*4 + half*2 + hlw
        const unsigned short* Bsrc = (role == 0 ? wsMT : wsWT) + ((size_t)lh * 4096);
        #pragma unroll
        for (int nt = 0; nt < 4; ++nt)
            #pragma unroll
            for (int k2 = 0; k2 < 2; ++k2)
                bfrag[nt][k2] = *(const bf8v*)(Bsrc + (nt * 16 + cl) * 64 + k2 * 32 + quad * 8);
    };
    auto load_pf = [&](int li) {
        const float* srcp = item_tables + ((size_t)gf * V_ + vidx[li]) * 64 + gseg * 16;
        #pragma unroll
        for (int j = 0; j < 4; ++j) pf[j] = ((const float4*)srcp)[j];
    };
    auto store_ue = [&]() {
        us8 u0, u1;
        u0[0] = f2bf(pf[0].x); u0[1] = f2bf(pf[0].y); u0[2] = f2bf(pf[0].z); u0[3] = f2bf(pf[0].w);
        u0[4] = f2bf(pf[1].x); u0[5] = f2bf(pf[1].y); u0[6] = f2bf(pf[1].z); u0[7] = f2bf(pf[1].w);
        u1[0] = f2bf(pf[2].x); u1[1] = f2bf(pf[2].y); u1[2] = f2bf(pf[2].z); u1[3] = f2bf(pf[2].w);
        u1[4] = f2bf(pf[3].x); u1[5] = f2bf(pf[3].y); u1[6] = f2bf(pf[3].z); u1[7] = f2bf(pf[3].w);
        *(us8*)&sUE[grow][gseg * 16]     = u0;
        *(us8*)&sUE[grow][gseg * 16 + 8] = u1;
    };

    load_pf(0);
    load_bfrag(lbase * 4 + hlw);
    store_ue();
    BARRIER();

    float lnacc[16];
    #pragma unroll
    for (int i = 0; i < 16; ++i) lnacc[i] = 0.f;

    for (int li = 0; li < lch; ++li) {
        const int l = lbase + li;

        if (li + 1 < lch) load_pf(li + 1);

        f4v accO[4];
        #pragma unroll
        for (int nt = 0; nt < 4; ++nt) accO[nt] = {0.f, 0.f, 0.f, 0.f};

        #pragma unroll
        for (int half = 0; half < 2; ++half) {
            // ---- phase A: waves 0,1 -> T; waves 2,3 -> Zt ----
            __builtin_amdgcn_s_setprio(1);
            #pragma unroll
            for (int m = 0; m < 4; ++m) {
                bf8v a0 = *(const bf8v*)&sUE[m * 16 + cl][quad * 8];
                bf8v a1 = *(const bf8v*)&sUE[m * 16 + cl][32 + quad * 8];
                #pragma unroll
                for (int nt = 0; nt < 4; ++nt) {
                    f4v acc = {0.f, 0.f, 0.f, 0.f};
                    acc = __builtin_amdgcn_mfma_f32_16x16x32_bf16(a0, bfrag[nt][0], acc, 0, 0, 0);
                    acc = __builtin_amdgcn_mfma_f32_16x16x32_bf16(a1, bfrag[nt][1], acc, 0, 0, 0);
                    if (role == 0) {
                        #pragma unroll
                        for (int j = 0; j < 4; ++j)
                            sT[m * 16 + quad * 4 + j][hlw * 64 + nt * 16 + cl] = f2bf(acc[j]);
                    } else {
                        ushort4 zp;
                        zp.x = f2bf(acc[0]); zp.y = f2bf(acc[1]);
                        zp.z = f2bf(acc[2]); zp.w = f2bf(acc[3]);
                        const int k0 = (quad >> 1) * 16 + hlw * 8 + (quad & 1) * 4;
                        *(ushort4*)&sZt[m][nt * 16 + cl][k0] = zp;
                    }
                }
            }
            __builtin_amdgcn_s_setprio(0);
            if (half == 0)          load_bfrag(l * 4 + 2 + hlw);
            else if (li + 1 < lch)  load_bfrag((l + 1) * 4 + hlw);
            BARRIER();

            // ---- scores + softmax + Ablk (wave = pair) ----
            {
                const int p = wv;
                const bool valid = (cl >> 3) == (quad >> 1);
                bf8v u0 = *(const bf8v*)&sUE[p * 16 + cl][quad * 8];
                bf8v u1 = *(const bf8v*)&sUE[p * 16 + cl][32 + quad * 8];
                #pragma unroll
                for (int hl = 0; hl < 2; ++hl) {
                    bf8v a0s = *(const bf8v*)&sT[p * 16 + cl][hl * 64 + quad * 8];
                    bf8v a1s = *(const bf8v*)&sT[p * 16 + cl][hl * 64 + 32 + quad * 8];
                    f4v acc = {0.f, 0.f, 0.f, 0.f};
                    acc = __builtin_amdgcn_mfma_f32_16x16x32_bf16(a0s, u0, acc, 0, 0, 0);
                    acc = __builtin_amdgcn_mfma_f32_16x16x32_bf16(a1s, u1, acc, 0, 0, 0);
                    const int kk = hl * 8 + (cl & 7) + (cl >> 3) * 16;
                    #pragma unroll
                    for (int j = 0; j < 4; ++j) {
                        float v = acc[j] * 0.125f;
                        float mx = v;
                        mx = fmaxf(mx, __shfl_xor(mx, 1));
                        mx = fmaxf(mx, __shfl_xor(mx, 2));
                        mx = fmaxf(mx, __shfl_xor(mx, 4));
                        float ex = __expf(v - mx);
                        float sm = ex;
                        sm += __shfl_xor(sm, 1);
                        sm += __shfl_xor(sm, 2);
                        sm += __shfl_xor(sm, 4);
                        float aw = valid ? ex * __builtin_amdgcn_rcpf(sm) : 0.f;
                        sAblk[p][quad * 4 + j][kk] = f2bf(aw);
                    }
                }
            }

            // ---- PV (same-wave sAblk dependency: no barrier needed) ----
            {
                const int p = wv;
                bf8v a0p = *(const bf8v*)&sAblk[p][cl][quad * 8];
                __builtin_amdgcn_s_setprio(1);
                #pragma unroll
                for (int nt = 0; nt < 4; ++nt) {
                    bf8v bz = *(const bf8v*)&sZt[p][nt * 16 + cl][quad * 8];
                    accO[nt] = __builtin_amdgcn_mfma_f32_16x16x32_bf16(a0p, bz, accO[nt], 0, 0, 0);
                }
                __builtin_amdgcn_s_setprio(0);
            }

            if (half == 1) {
                // write next-l UE rows (wave's own rows) before the barrier
                if (li + 1 < lch) store_ue();
                // ---- LN hoisted BEFORE the barrier: registers + stable LDS
                // only (sLinb/sLng/sLnb), no dependence on barriered buffers.
                float x[16];
                #pragma unroll
                for (int nt = 0; nt < 4; ++nt)
                    #pragma unroll
                    for (int j = 0; j < 4; ++j)
                        x[nt * 4 + j] = accO[nt][j] + sLinb[li][nt * 16 + cl];
                #pragma unroll
                for (int j = 0; j < 4; ++j) {
                    float s = x[j] + x[4 + j] + x[8 + j] + x[12 + j];
                    #pragma unroll
                    for (int m = 1; m < 16; m <<= 1) s += __shfl_xor(s, m);
                    float mean = s * (1.f / 64.f);
                    float q = 0.f;
                    #pragma unroll
                    for (int nt = 0; nt < 4; ++nt) { float d = x[nt * 4 + j] - mean; q += d * d; }
                    #pragma unroll
                    for (int m = 1; m < 16; m <<= 1) q += __shfl_xor(q, m);
                    float rst = rsqrtf(q * (1.f / 64.f) + LN_EPS);
                    #pragma unroll
                    for (int nt = 0; nt < 4; ++nt) {
                        int col = nt * 16 + cl;
                        lnacc[nt * 4 + j] += (x[nt * 4 + j] - mean) * rst * sLng[col] + sLnb[col];
                    }
                }
            }
            BARRIER();
        }
    }

    #pragma unroll
    for (int j = 0; j < 4; ++j) {
        const int row = wv * 16 + quad * 4 + j;
        const int b = b0 + (row >> 3), f = row & 7;
        #pragma unroll
        for (int nt = 0; nt < 4; ++nt)
            atomicAdd(&ubs_acc[(size_t)b * 512 + f * 64 + nt * 16 + cl], lnacc[nt * 4 + j]);
    }
}

// ---------------------------------------------------------------------------
// partial gemm over K-range: acc += LDS-A-row . B-row,  dual chains.
// ---------------------------------------------------------------------------
__device__ __forceinline__ f4v gemm_krange(
    const unsigned short* sArow, const unsigned short* __restrict__ brow,
    int klo, int khi)
{
    f4v acc0 = {0.f, 0.f, 0.f, 0.f};
    f4v acc1 = {0.f, 0.f, 0.f, 0.f};
    int k0 = klo;
    for (; k0 + 64 <= khi; k0 += 64) {
        bf8v a0 = *(const bf8v*)(sArow + k0);
        bf8v b0 = *(const bf8v*)(brow + k0);
        bf8v a1 = *(const bf8v*)(sArow + k0 + 32);
        bf8v b1 = *(const bf8v*)(brow + k0 + 32);
        acc0 = __builtin_amdgcn_mfma_f32_16x16x32_bf16(a0, b0, acc0, 0, 0, 0);
        acc1 = __builtin_amdgcn_mfma_f32_16x16x32_bf16(a1, b1, acc1, 0, 0, 0);
    }
    if (k0 < khi) {
        bf8v a = *(const bf8v*)(sArow + k0);
        bf8v b = *(const bf8v*)(brow + k0);
        acc0 = __builtin_amdgcn_mfma_f32_16x16x32_bf16(a, b, acc0, 0, 0, 0);
    }
    #pragma unroll
    for (int j = 0; j < 4; ++j) acc0[j] += acc1[j];
    return acc0;
}

// ---------------------------------------------------------------------------
// LN-from-C into LDS bf16, 512-thread version (16 rows; row = t>>5, sub = t&31)
// ---------------------------------------------------------------------------
__device__ __forceinline__ void ln_rows_to_lds512(
    const float* __restrict__ Cd, int N, int m0,
    const float* __restrict__ g, const float* __restrict__ bb,
    unsigned short* sH, int lda, int t, float invN)
{
    const int r = t >> 5, sub = t & 31;
    const float* crow = Cd + (size_t)(m0 + r) * N;
    float s = 0.f, s2 = 0.f;
    for (int j = sub * 4; j < N; j += 128) {
        float4 x = *(const float4*)(crow + j);
        s  += x.x + x.y + x.z + x.w;
        s2 += x.x * x.x + x.y * x.y + x.z * x.z + x.w * x.w;
    }
    #pragma unroll
    for (int m = 1; m < 32; m <<= 1) { s += __shfl_xor(s, m); s2 += __shfl_xor(s2, m); }
    const float mean = s * invN;
    const float var  = s2 * invN - mean * mean;
    const float rst  = rsqrtf(fmaxf(var, 0.f) + LN_EPS);
    for (int j = sub * 4; j < N; j += 128) {
        float4 x = *(const float4*)(crow + j);
        ushort4 o;
        o.x = f2bf(fmaxf((x.x - mean) * rst * g[j]     + bb[j],     0.f));
        o.y = f2bf(fmaxf((x.y - mean) * rst * g[j + 1] + bb[j + 1], 0.f));
        o.z = f2bf(fmaxf((x.z - mean) * rst * g[j + 2] + bb[j + 2], 0.f));
        o.w = f2bf(fmaxf((x.w - mean) * rst * g[j + 3] + bb[j + 3], 0.f));
        *(ushort4*)&sH[r * lda + j] = o;
    }
}

// ---------------------------------------------------------------------------
// Kernel G1: X-build (LDS) + gemm1 split-K -> C1 f32.
// grid (16 n x 16 m) = 256 blocks x 512 threads (8 waves = 4 n-sub x 2 k-half).
// ---------------------------------------------------------------------------
#define XLD 1320
__global__ __launch_bounds__(512) void gemm1x_kernel(
    const float* __restrict__ ubs_acc,
    const int* __restrict__ target_ad, const int* __restrict__ profile_feature,
    const float* __restrict__ context,
    const float* __restrict__ item_tables, const float* __restrict__ profile_tables,
    const unsigned short* __restrict__ Wt1, const float* __restrict__ b1,
    float* __restrict__ C1)
{
    __shared__ __align__(16) unsigned short sX[16][XLD];   // 42,240 B
    __shared__ float sRed[4][16][16];                      //  4,096 B
    const int t = threadIdx.x;
    const int wv = t >> 6, lane = t & 63, quad = lane >> 4, cl = lane & 15;
    const int nw = wv & 3, kh = wv >> 2;
    const int m0 = (blockIdx.x >> 4) * 16;
    const int n0w = (blockIdx.x & 15) * 64 + nw * 16;

    {
        const int r = t >> 5, sub = t & 31;
        const int gb = m0 + r;
        #pragma unroll
        for (int k = 0; k < 11; ++k) {
            int cc = sub * 4 + k * 128;
            if (cc >= TOWER_IN_) break;
            float4 x;
            if (cc < 512) {
                x = *(const float4*)(ubs_acc + (size_t)gb * 512 + cc);
                x.x = fmaxf(x.x * 0.01f, 0.f); x.y = fmaxf(x.y * 0.01f, 0.f);
                x.z = fmaxf(x.z * 0.01f, 0.f); x.w = fmaxf(x.w * 0.01f, 0.f);
            } else if (cc < 1024) {
                int f = (cc - 512) >> 6, e = (cc - 512) & 63;
                x = *(const float4*)(item_tables + ((size_t)f * V_ + target_ad[gb * 8 + f]) * 64 + e);
            } else if (cc < 1280) {
                int pp = (cc - 1024) >> 6, e = (cc - 1024) & 63;
                x = *(const float4*)(profile_tables + ((size_t)pp * V_ + profile_feature[gb * 4 + pp]) * 64 + e);
            } else {
                x = *(const float4*)(context + (size_t)gb * 32 + (cc - 1280));
            }
            ushort4 o;
            o.x = f2bf(x.x); o.y = f2bf(x.y); o.z = f2bf(x.z); o.w = f2bf(x.w);
            *(ushort4*)&sX[r][cc] = o;
        }
    }
    __syncthreads();

    const unsigned short* arow = &sX[0][0] + cl * XLD + quad * 8;
    const unsigned short* brow = Wt1 + (size_t)(n0w + cl) * 1312 + quad * 8;
    f4v part = gemm_krange(arow, brow, kh ? 672 : 0, kh ? 1312 : 672);  // 672 = 21*32

    if (kh == 1) {
        #pragma unroll
        for (int j = 0; j < 4; ++j) sRed[nw][quad * 4 + j][cl] = part[j];
    }
    __syncthreads();
    if (kh == 0) {
        float bv = b1[n0w + cl];
        #pragma unroll
        for (int j = 0; j < 4; ++j)
            C1[(size_t)(m0 + quad * 4 + j) * 1024 + n0w + cl] =
                part[j] + sRed[nw][quad * 4 + j][cl] + bv;
    }
}

// ---------------------------------------------------------------------------
// Kernel G2: LN1(C1)+ReLU (LDS) + gemm2 split-K -> C2 f32.
// grid (8 n x 16 m) = 128 blocks x 512 threads.
// ---------------------------------------------------------------------------
#define H1LD 1032
__global__ __launch_bounds__(512) void gemm2f_kernel(
    const float* __restrict__ C1, const float* __restrict__ g1,
    const float* __restrict__ bb1,
    const unsigned short* __restrict__ Wt2, const float* __restrict__ b2,
    float* __restrict__ C2)
{
    __shared__ __align__(16) unsigned short sH[16][H1LD];  // 33,024 B
    __shared__ float sRed[4][16][16];                      //  4,096 B
    const int t = threadIdx.x;
    const int wv = t >> 6, lane = t & 63, quad = lane >> 4, cl = lane & 15;
    const int nw = wv & 3, kh = wv >> 2;
    const int m0 = (blockIdx.x >> 3) * 16;
    const int n0w = (blockIdx.x & 7) * 64 + nw * 16;

    ln_rows_to_lds512(C1, 1024, m0, g1, bb1, &sH[0][0], H1LD, t, 1.f / 1024.f);
    __syncthreads();

    const unsigned short* arow = &sH[0][0] + cl * H1LD + quad * 8;
    const unsigned short* brow = Wt2 + (size_t)(n0w + cl) * 1024 + quad * 8;
    f4v part = gemm_krange(arow, brow, kh ? 512 : 0, kh ? 1024 : 512);

    if (kh == 1) {
        #pragma unroll
        for (int j = 0; j < 4; ++j) sRed[nw][quad * 4 + j][cl] = part[j];
    }
    __syncthreads();
    if (kh == 0) {
        float bv = b2[n0w + cl];
        #pragma unroll
        for (int j = 0; j < 4; ++j)
            C2[(size_t)(m0 + quad * 4 + j) * 512 + n0w + cl] =
                part[j] + sRed[nw][quad * 4 + j][cl] + bv;
    }
}

// ---------------------------------------------------------------------------
// Kernel G3: LN2(C2)+ReLU (LDS) + gemm3 split-K + LN3 + ReLU + dot(w4) +
// sigmoid -> out.  grid = 16 blocks x 512 threads (16 rows each).
// ---------------------------------------------------------------------------
#define H2LD 520
__global__ __launch_bounds__(512) void gemm3f_kernel(
    const float* __restrict__ C2, const float* __restrict__ g2,
    const float* __restrict__ bb2,
    const unsigned short* __restrict__ Wt3, const float* __restrict__ b3,
    const float* __restrict__ g3, const float* __restrict__ bb3,
    const float* __restrict__ w4, const float* __restrict__ b4,
    float* __restrict__ out)
{
    __shared__ __align__(16) unsigned short sH[16][H2LD];  // 16,640 B
    __shared__ float sR3[16][256];                         // 16,384 B
    __shared__ float sS[4][16], sQ[4][16], sP[4][16];
    const int t = threadIdx.x;
    const int wv = t >> 6, lane = t & 63, quad = lane >> 4, cl = lane & 15;
    const int nw = wv & 3, kh = wv >> 2;
    const int m0 = blockIdx.x * 16;

    ln_rows_to_lds512(C2, 512, m0, g2, bb2, &sH[0][0], H2LD, t, 1.f / 512.f);
    __syncthreads();

    // gemm3: wave (nw,kh) covers cols nw*64..+64 (4 nt), K-half kh.
    f4v acc[4];
    const int klo = kh ? 256 : 0, khi = kh ? 512 : 256;
    #pragma unroll
    for (int nt = 0; nt < 4; ++nt) {
        const unsigned short* arow = &sH[0][0] + cl * H2LD + quad * 8;
        const unsigned short* brow = Wt3 + (size_t)(nw * 64 + nt * 16 + cl) * 512 + quad * 8;
        acc[nt] = gemm_krange(arow, brow, klo, khi);
    }
    if (kh == 1) {
        #pragma unroll
        for (int nt = 0; nt < 4; ++nt)
            #pragma unroll
            for (int j = 0; j < 4; ++j)
                sR3[quad * 4 + j][nw * 64 + nt * 16 + cl] = acc[nt][j];
    }
    __syncthreads();
    if (kh == 0) {
        #pragma unroll
        for (int nt = 0; nt < 4; ++nt) {
            float bv = b3[nw * 64 + nt * 16 + cl];
            #pragma unroll
            for (int j = 0; j < 4; ++j)
                acc[nt][j] += sR3[quad * 4 + j][nw * 64 + nt * 16 + cl] + bv;
        }
        #pragma unroll
        for (int j = 0; j < 4; ++j) {
            float s = acc[0][j] + acc[1][j] + acc[2][j] + acc[3][j];
            float q = acc[0][j]*acc[0][j] + acc[1][j]*acc[1][j] + acc[2][j]*acc[2][j] + acc[3][j]*acc[3][j];
            #pragma unroll
            for (int m = 1; m < 16; m <<= 1) { s += __shfl_xor(s, m); q += __shfl_xor(q, m); }
            if (cl == 0) { sS[nw][quad * 4 + j] = s; sQ[nw][quad * 4 + j] = q; }
        }
    }
    __syncthreads();
    if (kh == 0) {
        float meanr[4], rstdr[4];
        #pragma unroll
        for (int j = 0; j < 4; ++j) {
            const int row = quad * 4 + j;
            float s = sS[0][row] + sS[1][row] + sS[2][row] + sS[3][row];
            float q = sQ[0][row] + sQ[1][row] + sQ[2][row] + sQ[3][row];
            float mean = s * (1.f / 256.f);
            float var  = q * (1.f / 256.f) - mean * mean;
            meanr[j] = mean;
            rstdr[j] = rsqrtf(fmaxf(var, 0.f) + LN_EPS);
        }
        #pragma unroll
        for (int j = 0; j < 4; ++j) {
            float p = 0.f;
            #pragma unroll
            for (int nt = 0; nt < 4; ++nt) {
                const int col = nw * 64 + nt * 16 + cl;
                float h = fmaxf((acc[nt][j] - meanr[j]) * rstdr[j] * g3[col] + bb3[col], 0.f);
                p += h * w4[col];
            }
            #pragma unroll
            for (int m = 1; m < 16; m <<= 1) p += __shfl_xor(p, m);
            if (cl == 0) sP[nw][quad * 4 + j] = p;
        }
    }
    __syncthreads();
    if (t < 16) {
        float p = sP[0][t] + sP[1][t] + sP[2][t] + sP[3][t];
        out[m0 + t] = 1.f / (1.f + expf(-(p + b4[0])));
    }
}

// ---------------------------------------------------------------------------
extern "C" void kernel_launch(void* const* d_in, const int* in_sizes, int n_in,
                              void* d_out, int out_size, void* d_ws, size_t ws_size,
                              hipStream_t stream)
{
    (void)in_sizes; (void)n_in; (void)out_size; (void)ws_size;
    const int*   target_ad       = (const int*)d_in[0];
    const int*   ubs_feature     = (const int*)d_in[1];
    const int*   profile_feature = (const int*)d_in[2];
    const float* context         = (const float*)d_in[3];
    const float* item_tables     = (const float*)d_in[4];
    const float* profile_tables  = (const float*)d_in[5];
    const float* q_w   = (const float*)d_in[6];
    const float* k_w   = (const float*)d_in[7];
    const float* v_w   = (const float*)d_in[8];
    const float* lin_w = (const float*)d_in[9];
    const float* lin_b = (const float*)d_in[10];
    const float* ln_g  = (const float*)d_in[11];
    const float* ln_b  = (const float*)d_in[12];
    const float* t_w1  = (const float*)d_in[13];
    const float* t_b1  = (const float*)d_in[14];
    const float* t_g1  = (const float*)d_in[15];
    const float* t_bb1 = (const float*)d_in[16];
    const float* t_w2  = (const float*)d_in[17];
    const float* t_b2  = (const float*)d_in[18];
    const float* t_g2  = (const float*)d_in[19];
    const float* t_bb2 = (const float*)d_in[20];
    const float* t_w3  = (const float*)d_in[21];
    const float* t_b3  = (const float*)d_in[22];
    const float* t_g3  = (const float*)d_in[23];
    const float* t_bb3 = (const float*)d_in[24];
    const float* t_w4  = (const float*)d_in[25];
    const float* t_b4  = (const float*)d_in[26];

    char* ws = (char*)d_ws;
    unsigned short* wsMT = (unsigned short*)(ws);              //  3,276,800
    unsigned short* wsWT = (unsigned short*)(ws +  3276800);   //  3,276,800
    float* ubs_acc       = (float*)         (ws +  6553600);   //    524,288
    unsigned short* Wt1  = (unsigned short*)(ws +  7077888);   //  2,686,976
    unsigned short* Wt2  = (unsigned short*)(ws +  9764864);   //  1,048,576
    unsigned short* Wt3  = (unsigned short*)(ws + 10813440);   //    262,144
    float*          C1   = (float*)         (ws + 11075584);   //  1,048,576
    float*          C2   = (float*)         (ws + 12124160);   //    524,288 (end 12,648,448)

    pre_kernel<<<528, 256, 0, stream>>>(q_w, k_w, v_w, lin_w, wsMT, wsWT, ubs_acc);
    attn_kernel<<<ATTN_BLKS_ + 1952, 256, 0, stream>>>(ubs_feature, item_tables, wsMT, wsWT,
                                                       lin_b, ln_g, ln_b, ubs_acc,
                                                       t_w1, t_w2, t_w3, Wt1, Wt2, Wt3);
    gemm1x_kernel<<<256, 512, 0, stream>>>(ubs_acc, target_ad, profile_feature, context,
                                           item_tables, profile_tables, Wt1, t_b1, C1);
    gemm2f_kernel<<<128, 512, 0, stream>>>(C1, t_g1, t_bb1, Wt2, t_b2, C2);
    gemm3f_kernel<<<16, 512, 0, stream>>>(C2, t_g2, t_bb2, Wt3, t_b3,
                                          t_g3, t_bb3, t_w4, t_b4, (float*)d_out);
}